// Round 1
// baseline (154.715 us; speedup 1.0000x reference)
//
#include <hip/hip_runtime.h>

// CirculantSSMLayer on MI355X.
// Pipeline: LN -> bf16 MFMA GEMM (Wa|WB fused) -> packed real FFT256 (a+iu trick)
//           -> per-(b,k) block-scan over T -> packed inverse FFT -> bf16 MFMA GEMM + epilogue.
// Spectra stored [b][k][t] (129 bins) so the time scan is fully coalesced.

typedef unsigned short ushort_t;
typedef short s16x8 __attribute__((ext_vector_type(8)));
typedef float f32x4 __attribute__((ext_vector_type(4)));

#define B_ 4
#define T_ 4096
#define D_ 1024
#define N_ 256
#define KB_ 129
#define M_ (B_*T_)

__device__ __forceinline__ ushort_t f2bf(float f) {
  unsigned u = __float_as_uint(f);
  u = (u + 0x7FFFu + ((u >> 16) & 1u)) >> 16;
  return (ushort_t)u;
}
__device__ __forceinline__ float2 cmul(float2 a, float2 b) {
  return make_float2(a.x*b.x - a.y*b.y, a.x*b.y + a.y*b.x);
}

// ---------------- weight prep: f32 -> bf16 ----------------
__global__ __launch_bounds__(256) void prep_w(const float* __restrict__ Wa,
    const float* __restrict__ WB, const float* __restrict__ WC,
    ushort_t* __restrict__ Wab, ushort_t* __restrict__ WCb) {
  int i = blockIdx.x * 256 + threadIdx.x;
  const int nab = 512 * 1024;
  if (i < nab) {
    float v = (i < 256 * 1024) ? Wa[i] : WB[i - 256 * 1024];
    Wab[i] = f2bf(v);
  } else {
    int j = i - nab;
    if (j < 1024 * 256) WCb[j] = f2bf(WC[j]);
  }
}

// ---------------- layernorm -> bf16 ----------------
__global__ __launch_bounds__(256) void ln_kernel(const float* __restrict__ x,
    const float* __restrict__ w, const float* __restrict__ bb,
    ushort_t* __restrict__ xn) {
  int row = blockIdx.x, tid = threadIdx.x;
  const float4* xr = (const float4*)(x + (size_t)row * D_);
  float4 v = xr[tid];
  float s  = v.x + v.y + v.z + v.w;
  float sq = v.x*v.x + v.y*v.y + v.z*v.z + v.w*v.w;
  #pragma unroll
  for (int off = 32; off >= 1; off >>= 1) {
    s  += __shfl_xor(s, off);
    sq += __shfl_xor(sq, off);
  }
  __shared__ float red[8];
  if ((tid & 63) == 0) { red[tid >> 6] = s; red[4 + (tid >> 6)] = sq; }
  __syncthreads();
  s  = red[0] + red[1] + red[2] + red[3];
  sq = red[4] + red[5] + red[6] + red[7];
  float mu  = s * (1.0f / D_);
  float var = sq * (1.0f / D_) - mu * mu;
  float rs  = rsqrtf(var + 1e-5f);
  float4 wv = ((const float4*)w)[tid];
  float4 bv = ((const float4*)bb)[tid];
  ushort4 o;
  o.x = f2bf((v.x - mu) * rs * wv.x + bv.x);
  o.y = f2bf((v.y - mu) * rs * wv.y + bv.y);
  o.z = f2bf((v.z - mu) * rs * wv.z + bv.z);
  o.w = f2bf((v.w - mu) * rs * wv.w + bv.w);
  ((ushort4*)(xn + (size_t)row * D_))[tid] = o;
}

// ---------------- bf16 MFMA GEMM: C[m][n] = sum_k A[m][k]*B[n][k] ----------------
// 128x128 tile, BK=32, 4 waves (2x2), 16x16x32 MFMA, LDS padded to 40 shorts/row.
template<bool EPI>
__global__ __launch_bounds__(256) void gemm_bf16(
    const ushort_t* __restrict__ A, int lda,
    const ushort_t* __restrict__ B, int ldb,
    float* __restrict__ C, int ldc,
    int K, int ntiles,
    const float* __restrict__ bias,
    const float* __restrict__ dskip,
    const float* __restrict__ xres) {
  __shared__ ushort_t Alds[128][40];
  __shared__ ushort_t Blds[128][40];
  int bid = blockIdx.x;
  int mt = bid / ntiles, nt = bid % ntiles;
  int m0 = mt * 128, n0 = nt * 128;
  int tid = threadIdx.x;
  int lane = tid & 63, wid = tid >> 6;
  int wm = wid >> 1, wn = wid & 1;

  f32x4 acc[4][4] = {};

  for (int k0 = 0; k0 < K; k0 += 32) {
    __syncthreads();
    #pragma unroll
    for (int c = tid; c < 512; c += 256) {
      int row = c >> 2, ko = (c & 3) * 8;
      *reinterpret_cast<int4*>(&Alds[row][ko]) =
          *reinterpret_cast<const int4*>(A + (size_t)(m0 + row) * lda + k0 + ko);
      *reinterpret_cast<int4*>(&Blds[row][ko]) =
          *reinterpret_cast<const int4*>(B + (size_t)(n0 + row) * ldb + k0 + ko);
    }
    __syncthreads();
    int koff = (lane >> 4) * 8;
    int rbase = lane & 15;
    s16x8 af[4], bf[4];
    #pragma unroll
    for (int i = 0; i < 4; ++i) {
      af[i] = *reinterpret_cast<const s16x8*>(&Alds[wm * 64 + i * 16 + rbase][koff]);
      bf[i] = *reinterpret_cast<const s16x8*>(&Blds[wn * 64 + i * 16 + rbase][koff]);
    }
    #pragma unroll
    for (int i = 0; i < 4; ++i)
      #pragma unroll
      for (int j = 0; j < 4; ++j)
        acc[i][j] = __builtin_amdgcn_mfma_f32_16x16x32_bf16(af[i], bf[j], acc[i][j], 0, 0, 0);
  }

  int r0 = (lane >> 4) * 4, cc = lane & 15;
  #pragma unroll
  for (int i = 0; i < 4; ++i) {
    #pragma unroll
    for (int j = 0; j < 4; ++j) {
      int col = n0 + wn * 64 + j * 16 + cc;
      #pragma unroll
      for (int r = 0; r < 4; ++r) {
        int row = m0 + wm * 64 + i * 16 + r0 + r;
        float v = acc[i][j][r];
        if constexpr (EPI) v += bias[col] + dskip[col] * xres[(size_t)row * ldc + col];
        C[(size_t)row * ldc + col] = v;
      }
    }
  }
}

// ---------------- forward: bias+tanh+gate, packed FFT256, gate-by-magnitude ----------------
// Block: 512 threads = 8 rows (one wave each). z = a + i*u, one FFT serves both.
__global__ __launch_bounds__(512) void fft_fwd(const float* __restrict__ au,
    const float* __restrict__ ba, const float* __restrict__ bu,
    const float* __restrict__ lg, float2* __restrict__ ah, float2* __restrict__ uh) {
  __shared__ float2 Z[8][256];
  int tid = threadIdx.x;
  int m0 = blockIdx.x * 8;
  int tg = tid >> 6, lane = tid & 63;
  float gamma = 1.f / (1.f + __expf(-lg[0]));
  const float* row = au + (size_t)(m0 + tg) * (2 * N_);
  #pragma unroll
  for (int j = 0; j < 4; ++j) {
    int n = lane + 64 * j;
    float a = gamma * tanhf(row[n] + ba[n]);
    float u = row[N_ + n] + bu[n];
    Z[tg][__brev((unsigned)n) >> 24] = make_float2(a, u);
  }
  __syncthreads();
  #pragma unroll
  for (int len = 2; len <= 256; len <<= 1) {
    int half = len >> 1;
    float ang = -6.2831853071795864f / (float)len;
    #pragma unroll
    for (int s = 0; s < 2; ++s) {
      int bi = lane + 64 * s;
      int j = bi & (half - 1);
      int i0 = ((bi & ~(half - 1)) << 1) | j;
      int i1 = i0 + half;
      float sn, cs;
      __sincosf(ang * (float)j, &sn, &cs);
      float2 z0 = Z[tg][i0], z1 = Z[tg][i1];
      float2 t = make_float2(cs * z1.x - sn * z1.y, cs * z1.y + sn * z1.x);
      Z[tg][i1] = make_float2(z0.x - t.x, z0.y - t.y);
      Z[tg][i0] = make_float2(z0.x + t.x, z0.y + t.y);
    }
    __syncthreads();
  }
  // extract A(k), U(k) for k=0..128, gate A, write [b][k][t] with full 64B lines
  int b = m0 >> 12, tb = m0 & (T_ - 1);
  #pragma unroll
  for (int p = 0; p < 3; ++p) {
    int k = (tid >> 3) + p * 64;
    int tl = tid & 7;
    if (k <= 128) {
      float2 zk = Z[tl][k];
      float2 zn = Z[tl][(256 - k) & 255];
      float2 Af = make_float2(0.5f * (zk.x + zn.x), 0.5f * (zk.y - zn.y));
      float2 Uf = make_float2(0.5f * (zk.y + zn.y), -0.5f * (zk.x - zn.x));
      float mag = fmaxf(sqrtf(Af.x * Af.x + Af.y * Af.y), 1e-8f);
      float scl = 1.f / (1.f + __expf(-2.f * (1.f - mag)));
      Af.x *= scl; Af.y *= scl;
      size_t off = ((size_t)(b * KB_ + k)) * T_ + tb + tl;
      ah[off] = Af;
      uh[off] = Uf;
    }
  }
}

// ---------------- time scan: h_t = a_t*h_{t-1} + u_t per (b,k) chain ----------------
// One block per chain; 512 threads x 8 elements; Hillis-Steele over thread composites.
__global__ __launch_bounds__(512) void scan_kernel(const float2* __restrict__ ah,
                                                   float2* __restrict__ uh) {
  __shared__ float4 sc[2][512];
  int tid = threadIdx.x;
  size_t base = (size_t)blockIdx.x * T_;
  const float4* a4 = (const float4*)(ah + base);
  float4* u4 = (float4*)(uh + base);
  float4 Av[4], Uv[4];
  #pragma unroll
  for (int q = 0; q < 4; ++q) { Av[q] = a4[tid * 4 + q]; Uv[q] = u4[tid * 4 + q]; }
  float2 La[8], Lb[8];
  float2 ra = make_float2(1.f, 0.f), rb = make_float2(0.f, 0.f);
  #pragma unroll
  for (int e = 0; e < 8; ++e) {
    int q = e >> 1;
    float2 a, u;
    if (e & 1) { a = make_float2(Av[q].z, Av[q].w); u = make_float2(Uv[q].z, Uv[q].w); }
    else       { a = make_float2(Av[q].x, Av[q].y); u = make_float2(Uv[q].x, Uv[q].y); }
    float2 t = cmul(a, rb);
    rb = make_float2(t.x + u.x, t.y + u.y);
    ra = cmul(ra, a);
    La[e] = ra; Lb[e] = rb;
  }
  sc[0][tid] = make_float4(ra.x, ra.y, rb.x, rb.y);
  __syncthreads();
  int buf = 0;
  for (int off = 1; off < 512; off <<= 1) {
    float4 cur = sc[buf][tid];
    if (tid >= off) {
      float4 pre = sc[buf][tid - off];
      float2 A1 = make_float2(pre.x, pre.y), B1 = make_float2(pre.z, pre.w);
      float2 A2 = make_float2(cur.x, cur.y), B2 = make_float2(cur.z, cur.w);
      float2 Ax = cmul(A1, A2);
      float2 t  = cmul(A2, B1);
      cur = make_float4(Ax.x, Ax.y, t.x + B2.x, t.y + B2.y);
    }
    sc[buf ^ 1][tid] = cur;
    __syncthreads();
    buf ^= 1;
  }
  float2 Pb = make_float2(0.f, 0.f);
  if (tid > 0) { float4 pv = sc[buf][tid - 1]; Pb = make_float2(pv.z, pv.w); }
  #pragma unroll
  for (int q = 0; q < 4; ++q) {
    float2 h0 = cmul(La[2 * q], Pb);
    h0.x += Lb[2 * q].x; h0.y += Lb[2 * q].y;
    float2 h1 = cmul(La[2 * q + 1], Pb);
    h1.x += Lb[2 * q + 1].x; h1.y += Lb[2 * q + 1].y;
    u4[tid * 4 + q] = make_float4(h0.x, h0.y, h1.x, h1.y);
  }
}

// ---------------- inverse FFT: 2 real rows per complex transform -> h bf16 ----------------
// Block: 256 threads = 8 rows = 4 transforms (one wave each).
__global__ __launch_bounds__(256) void ifft_kernel(const float2* __restrict__ hh,
                                                   ushort_t* __restrict__ hb) {
  __shared__ float2 Hraw[8][132];
  __shared__ float2 Wz[4][256];
  int tid = threadIdx.x;
  int m0 = blockIdx.x * 8;
  int b = m0 >> 12, tb = m0 & (T_ - 1);
  #pragma unroll
  for (int p = 0; p < 5; ++p) {
    int k = p * 32 + (tid >> 3), tl = tid & 7;
    if (k <= 128) Hraw[tl][k] = hh[((size_t)(b * KB_ + k)) * T_ + tb + tl];
  }
  __syncthreads();
  #pragma unroll
  for (int p = 0; p < 3; ++p) {
    int idx = p * 256 + tid;
    if (idx < 516) {
      int k = idx >> 2, pr = idx & 3;
      float2 h1 = Hraw[2 * pr][k], h2 = Hraw[2 * pr + 1][k];
      Wz[pr][__brev((unsigned)k) >> 24] = make_float2(h1.x - h2.y, h1.y + h2.x);
      if (k >= 1 && k <= 127)
        Wz[pr][__brev((unsigned)(256 - k)) >> 24] = make_float2(h1.x + h2.y, h2.x - h1.y);
    }
  }
  __syncthreads();
  int pr = tid >> 6, lane = tid & 63;
  #pragma unroll
  for (int len = 2; len <= 256; len <<= 1) {
    int half = len >> 1;
    float ang = 6.2831853071795864f / (float)len;
    #pragma unroll
    for (int s = 0; s < 2; ++s) {
      int bi = lane + 64 * s;
      int j = bi & (half - 1);
      int i0 = ((bi & ~(half - 1)) << 1) | j;
      int i1 = i0 + half;
      float sn, cs;
      __sincosf(ang * (float)j, &sn, &cs);
      float2 z0 = Wz[pr][i0], z1 = Wz[pr][i1];
      float2 t = make_float2(cs * z1.x - sn * z1.y, cs * z1.y + sn * z1.x);
      Wz[pr][i1] = make_float2(z0.x - t.x, z0.y - t.y);
      Wz[pr][i0] = make_float2(z0.x + t.x, z0.y + t.y);
    }
    __syncthreads();
  }
  const float inv = 1.f / 256.f;
  #pragma unroll
  for (int j = 0; j < 4; ++j) {
    int n = lane + 64 * j;
    float2 wv = Wz[pr][n];
    hb[(size_t)(m0 + 2 * pr) * N_ + n]     = f2bf(wv.x * inv);
    hb[(size_t)(m0 + 2 * pr + 1) * N_ + n] = f2bf(wv.y * inv);
  }
}

// ---------------- launch ----------------
extern "C" void kernel_launch(void* const* d_in, const int* in_sizes, int n_in,
                              void* d_out, int out_size, void* d_ws, size_t ws_size,
                              hipStream_t stream) {
  const float* x      = (const float*)d_in[0];
  const float* Wa_w   = (const float*)d_in[1];
  const float* Wa_b   = (const float*)d_in[2];
  const float* lg     = (const float*)d_in[3];
  const float* WB_w   = (const float*)d_in[4];
  const float* WB_b   = (const float*)d_in[5];
  const float* WC_w   = (const float*)d_in[6];
  const float* WC_b   = (const float*)d_in[7];
  const float* D_skip = (const float*)d_in[8];
  const float* ln_w   = (const float*)d_in[9];
  const float* ln_b   = (const float*)d_in[10];
  float* out = (float*)d_out;
  char* ws = (char*)d_ws;

  // Workspace layout (lifetime-overlapped):
  //   [0, 33.55MB): xn bf16 (early)  |  ah+uh float2 spectra (late, 33.82MB incl. Wab slot)
  //   [33.55MB, 34.60MB): Wab bf16 (early, clobbered by uh tail later)
  //   [34.60MB, 35.13MB): WC bf16 (whole run)
  //   [35.13MB, 68.68MB): au_pre f32 (early) | h bf16 (late)
  ushort_t* xn  = (ushort_t*)(ws + 0);
  ushort_t* Wab = (ushort_t*)(ws + 33554432);
  ushort_t* WCb = (ushort_t*)(ws + 34603008);
  float*    au  = (float*)(ws + 35127296);
  ushort_t* hb  = (ushort_t*)(ws + 35127296);  // aliases au (dead by then)
  float2*   ah  = (float2*)(ws + 0);           // aliases xn (dead by then)
  float2*   uh  = (float2*)(ws + 16908288);    // h_hat written in place

  prep_w<<<3072, 256, 0, stream>>>(Wa_w, WB_w, WC_w, Wab, WCb);
  ln_kernel<<<M_, 256, 0, stream>>>(x, ln_w, ln_b, xn);
  gemm_bf16<false><<<512, 256, 0, stream>>>(xn, D_, Wab, D_, au, 512, D_, 4,
                                            nullptr, nullptr, nullptr);
  fft_fwd<<<M_ / 8, 512, 0, stream>>>(au, Wa_b, WB_b, lg, ah, uh);
  scan_kernel<<<B_ * KB_, 512, 0, stream>>>(ah, uh);
  ifft_kernel<<<M_ / 8, 256, 0, stream>>>(uh, hb);
  gemm_bf16<true><<<1024, 256, 0, stream>>>(hb, N_, WCb, N_, out, D_, N_, 8,
                                            WC_b, D_skip, x);
}

// Round 2
// 144.731 us; speedup vs baseline: 1.0690x; 1.0690x over previous
//
#include <hip/hip_runtime.h>

// CirculantSSMLayer on MI355X.
// Pipeline: LN -> bf16 MFMA GEMM (Wa|WB fused) -> packed real FFT256 (a+iu trick)
//           -> per-(b,k) block-scan over T -> packed inverse FFT -> bf16 MFMA GEMM + epilogue.
// R2: GEMMs rebuilt on the m97 structure: global_load_lds width-16, linear LDS,
//     2-barrier K-loop, XCD-aware block swizzle.

typedef unsigned short ushort_t;
typedef short s16x8 __attribute__((ext_vector_type(8)));
typedef float f32x4 __attribute__((ext_vector_type(4)));

#define B_ 4
#define T_ 4096
#define D_ 1024
#define N_ 256
#define KB_ 129
#define M_ (B_*T_)

__device__ __forceinline__ ushort_t f2bf(float f) {
  unsigned u = __float_as_uint(f);
  u = (u + 0x7FFFu + ((u >> 16) & 1u)) >> 16;
  return (ushort_t)u;
}
__device__ __forceinline__ float2 cmul(float2 a, float2 b) {
  return make_float2(a.x*b.x - a.y*b.y, a.x*b.y + a.y*b.x);
}

typedef const __attribute__((address_space(1))) unsigned glb_u32;
typedef __attribute__((address_space(3))) unsigned lds_u32;
__device__ __forceinline__ void gload16(const void* g, void* l) {
  __builtin_amdgcn_global_load_lds((glb_u32*)g, (lds_u32*)l, 16, 0, 0);
}

// ---------------- weight prep: f32 -> bf16 ----------------
__global__ __launch_bounds__(256) void prep_w(const float* __restrict__ Wa,
    const float* __restrict__ WB, const float* __restrict__ WC,
    ushort_t* __restrict__ Wab, ushort_t* __restrict__ WCb) {
  int i = blockIdx.x * 256 + threadIdx.x;
  const int nab = 512 * 1024;
  if (i < nab) {
    float v = (i < 256 * 1024) ? Wa[i] : WB[i - 256 * 1024];
    Wab[i] = f2bf(v);
  } else {
    int j = i - nab;
    if (j < 1024 * 256) WCb[j] = f2bf(WC[j]);
  }
}

// ---------------- layernorm -> bf16 ----------------
__global__ __launch_bounds__(256) void ln_kernel(const float* __restrict__ x,
    const float* __restrict__ w, const float* __restrict__ bb,
    ushort_t* __restrict__ xn) {
  int row = blockIdx.x, tid = threadIdx.x;
  const float4* xr = (const float4*)(x + (size_t)row * D_);
  float4 v = xr[tid];
  float s  = v.x + v.y + v.z + v.w;
  float sq = v.x*v.x + v.y*v.y + v.z*v.z + v.w*v.w;
  #pragma unroll
  for (int off = 32; off >= 1; off >>= 1) {
    s  += __shfl_xor(s, off);
    sq += __shfl_xor(sq, off);
  }
  __shared__ float red[8];
  if ((tid & 63) == 0) { red[tid >> 6] = s; red[4 + (tid >> 6)] = sq; }
  __syncthreads();
  s  = red[0] + red[1] + red[2] + red[3];
  sq = red[4] + red[5] + red[6] + red[7];
  float mu  = s * (1.0f / D_);
  float var = sq * (1.0f / D_) - mu * mu;
  float rs  = rsqrtf(var + 1e-5f);
  float4 wv = ((const float4*)w)[tid];
  float4 bv = ((const float4*)bb)[tid];
  ushort4 o;
  o.x = f2bf((v.x - mu) * rs * wv.x + bv.x);
  o.y = f2bf((v.y - mu) * rs * wv.y + bv.y);
  o.z = f2bf((v.z - mu) * rs * wv.z + bv.z);
  o.w = f2bf((v.w - mu) * rs * wv.w + bv.w);
  ((ushort4*)(xn + (size_t)row * D_))[tid] = o;
}

// ---------------- bf16 MFMA GEMM: C[m][n] = sum_k A[m][k]*B[n][k] ----------------
// m97 structure: 128x128 tile, BK=32, 4 waves (2x2), 16x16x32 MFMA,
// linear LDS [128][32], global_load_lds width-16, 2 barriers per K-step.
template<bool EPI>
__global__ __launch_bounds__(256) void gemm_bf16(
    const ushort_t* __restrict__ A, int lda,
    const ushort_t* __restrict__ B, int ldb,
    float* __restrict__ C, int ldc,
    int K, int ntiles,
    const float* __restrict__ bias,
    const float* __restrict__ dskip,
    const float* __restrict__ xres) {
  __shared__ ushort_t Alds[128 * 32];
  __shared__ ushort_t Blds[128 * 32];
  // bijective XCD swizzle (gridDim %8 == 0): each XCD gets a contiguous chunk
  int bid = blockIdx.x;
  int cpx = gridDim.x >> 3;
  bid = (bid & 7) * cpx + (bid >> 3);
  int mt = bid / ntiles, nt = bid % ntiles;
  int m0 = mt * 128, n0 = nt * 128;
  int tid = threadIdx.x;
  int lane = tid & 63, wid = tid >> 6;
  int wm = wid >> 1, wn = wid & 1;

  // staging: wave w stages rows [32w, 32w+32) of both tiles; 1KB per instruction
  // (16 rows x 64B). lane -> row 16c + (lane>>2), col (lane&3)*8 shorts.
  int srow = wid * 32 + (lane >> 2);
  int scol = (lane & 3) * 8;
  const ushort_t* gA0 = A + (size_t)(m0 + srow) * lda + scol;
  const ushort_t* gA1 = A + (size_t)(m0 + srow + 16) * lda + scol;
  const ushort_t* gB0 = B + (size_t)(n0 + srow) * ldb + scol;
  const ushort_t* gB1 = B + (size_t)(n0 + srow + 16) * ldb + scol;
  ushort_t* lA0 = &Alds[(wid * 32) * 32];
  ushort_t* lA1 = &Alds[(wid * 32 + 16) * 32];
  ushort_t* lB0 = &Blds[(wid * 32) * 32];
  ushort_t* lB1 = &Blds[(wid * 32 + 16) * 32];

  f32x4 acc[4][4] = {};
  int koff = (lane >> 4) * 8;
  int rbase = lane & 15;

  for (int k0 = 0; k0 < K; k0 += 32) {
    __syncthreads();
    gload16(gA0 + k0, lA0);
    gload16(gA1 + k0, lA1);
    gload16(gB0 + k0, lB0);
    gload16(gB1 + k0, lB1);
    __syncthreads();   // compiler emits vmcnt(0) drain before s_barrier
    s16x8 af[4], bf[4];
    #pragma unroll
    for (int i = 0; i < 4; ++i) {
      af[i] = *reinterpret_cast<const s16x8*>(&Alds[(wm * 64 + i * 16 + rbase) * 32 + koff]);
      bf[i] = *reinterpret_cast<const s16x8*>(&Blds[(wn * 64 + i * 16 + rbase) * 32 + koff]);
    }
    #pragma unroll
    for (int i = 0; i < 4; ++i)
      #pragma unroll
      for (int j = 0; j < 4; ++j)
        acc[i][j] = __builtin_amdgcn_mfma_f32_16x16x32_bf16(af[i], bf[j], acc[i][j], 0, 0, 0);
  }

  int r0 = (lane >> 4) * 4, cc = lane & 15;
  #pragma unroll
  for (int i = 0; i < 4; ++i) {
    #pragma unroll
    for (int j = 0; j < 4; ++j) {
      int col = n0 + wn * 64 + j * 16 + cc;
      #pragma unroll
      for (int r = 0; r < 4; ++r) {
        int row = m0 + wm * 64 + i * 16 + r0 + r;
        float v = acc[i][j][r];
        if constexpr (EPI) v += bias[col] + dskip[col] * xres[(size_t)row * ldc + col];
        C[(size_t)row * ldc + col] = v;
      }
    }
  }
}

// ---------------- forward: bias+tanh+gate, packed FFT256, gate-by-magnitude ----------------
// Block: 512 threads = 8 rows (one wave each). z = a + i*u, one FFT serves both.
__global__ __launch_bounds__(512) void fft_fwd(const float* __restrict__ au,
    const float* __restrict__ ba, const float* __restrict__ bu,
    const float* __restrict__ lg, float2* __restrict__ ah, float2* __restrict__ uh) {
  __shared__ float2 Z[8][256];
  int tid = threadIdx.x;
  int m0 = blockIdx.x * 8;
  int tg = tid >> 6, lane = tid & 63;
  float gamma = 1.f / (1.f + __expf(-lg[0]));
  const float* row = au + (size_t)(m0 + tg) * (2 * N_);
  #pragma unroll
  for (int j = 0; j < 4; ++j) {
    int n = lane + 64 * j;
    float a = gamma * tanhf(row[n] + ba[n]);
    float u = row[N_ + n] + bu[n];
    Z[tg][__brev((unsigned)n) >> 24] = make_float2(a, u);
  }
  __syncthreads();
  #pragma unroll
  for (int len = 2; len <= 256; len <<= 1) {
    int half = len >> 1;
    float ang = -6.2831853071795864f / (float)len;
    #pragma unroll
    for (int s = 0; s < 2; ++s) {
      int bi = lane + 64 * s;
      int j = bi & (half - 1);
      int i0 = ((bi & ~(half - 1)) << 1) | j;
      int i1 = i0 + half;
      float sn, cs;
      __sincosf(ang * (float)j, &sn, &cs);
      float2 z0 = Z[tg][i0], z1 = Z[tg][i1];
      float2 t = make_float2(cs * z1.x - sn * z1.y, cs * z1.y + sn * z1.x);
      Z[tg][i1] = make_float2(z0.x - t.x, z0.y - t.y);
      Z[tg][i0] = make_float2(z0.x + t.x, z0.y + t.y);
    }
    __syncthreads();
  }
  // extract A(k), U(k) for k=0..128, gate A, write [b][k][t] with full 64B lines
  int b = m0 >> 12, tb = m0 & (T_ - 1);
  #pragma unroll
  for (int p = 0; p < 3; ++p) {
    int k = (tid >> 3) + p * 64;
    int tl = tid & 7;
    if (k <= 128) {
      float2 zk = Z[tl][k];
      float2 zn = Z[tl][(256 - k) & 255];
      float2 Af = make_float2(0.5f * (zk.x + zn.x), 0.5f * (zk.y - zn.y));
      float2 Uf = make_float2(0.5f * (zk.y + zn.y), -0.5f * (zk.x - zn.x));
      float mag = fmaxf(sqrtf(Af.x * Af.x + Af.y * Af.y), 1e-8f);
      float scl = 1.f / (1.f + __expf(-2.f * (1.f - mag)));
      Af.x *= scl; Af.y *= scl;
      size_t off = ((size_t)(b * KB_ + k)) * T_ + tb + tl;
      ah[off] = Af;
      uh[off] = Uf;
    }
  }
}

// ---------------- time scan: h_t = a_t*h_{t-1} + u_t per (b,k) chain ----------------
// One block per chain; 512 threads x 8 elements; Hillis-Steele over thread composites.
__global__ __launch_bounds__(512) void scan_kernel(const float2* __restrict__ ah,
                                                   float2* __restrict__ uh) {
  __shared__ float4 sc[2][512];
  int tid = threadIdx.x;
  size_t base = (size_t)blockIdx.x * T_;
  const float4* a4 = (const float4*)(ah + base);
  float4* u4 = (float4*)(uh + base);
  float4 Av[4], Uv[4];
  #pragma unroll
  for (int q = 0; q < 4; ++q) { Av[q] = a4[tid * 4 + q]; Uv[q] = u4[tid * 4 + q]; }
  float2 La[8], Lb[8];
  float2 ra = make_float2(1.f, 0.f), rb = make_float2(0.f, 0.f);
  #pragma unroll
  for (int e = 0; e < 8; ++e) {
    int q = e >> 1;
    float2 a, u;
    if (e & 1) { a = make_float2(Av[q].z, Av[q].w); u = make_float2(Uv[q].z, Uv[q].w); }
    else       { a = make_float2(Av[q].x, Av[q].y); u = make_float2(Uv[q].x, Uv[q].y); }
    float2 t = cmul(a, rb);
    rb = make_float2(t.x + u.x, t.y + u.y);
    ra = cmul(ra, a);
    La[e] = ra; Lb[e] = rb;
  }
  sc[0][tid] = make_float4(ra.x, ra.y, rb.x, rb.y);
  __syncthreads();
  int buf = 0;
  for (int off = 1; off < 512; off <<= 1) {
    float4 cur = sc[buf][tid];
    if (tid >= off) {
      float4 pre = sc[buf][tid - off];
      float2 A1 = make_float2(pre.x, pre.y), B1 = make_float2(pre.z, pre.w);
      float2 A2 = make_float2(cur.x, cur.y), B2 = make_float2(cur.z, cur.w);
      float2 Ax = cmul(A1, A2);
      float2 t  = cmul(A2, B1);
      cur = make_float4(Ax.x, Ax.y, t.x + B2.x, t.y + B2.y);
    }
    sc[buf ^ 1][tid] = cur;
    __syncthreads();
    buf ^= 1;
  }
  float2 Pb = make_float2(0.f, 0.f);
  if (tid > 0) { float4 pv = sc[buf][tid - 1]; Pb = make_float2(pv.z, pv.w); }
  #pragma unroll
  for (int q = 0; q < 4; ++q) {
    float2 h0 = cmul(La[2 * q], Pb);
    h0.x += Lb[2 * q].x; h0.y += Lb[2 * q].y;
    float2 h1 = cmul(La[2 * q + 1], Pb);
    h1.x += Lb[2 * q + 1].x; h1.y += Lb[2 * q + 1].y;
    u4[tid * 4 + q] = make_float4(h0.x, h0.y, h1.x, h1.y);
  }
}

// ---------------- inverse FFT: 2 real rows per complex transform -> h bf16 ----------------
// Block: 256 threads = 8 rows = 4 transforms (one wave each).
__global__ __launch_bounds__(256) void ifft_kernel(const float2* __restrict__ hh,
                                                   ushort_t* __restrict__ hb) {
  __shared__ float2 Hraw[8][132];
  __shared__ float2 Wz[4][256];
  int tid = threadIdx.x;
  int m0 = blockIdx.x * 8;
  int b = m0 >> 12, tb = m0 & (T_ - 1);
  #pragma unroll
  for (int p = 0; p < 5; ++p) {
    int k = p * 32 + (tid >> 3), tl = tid & 7;
    if (k <= 128) Hraw[tl][k] = hh[((size_t)(b * KB_ + k)) * T_ + tb + tl];
  }
  __syncthreads();
  #pragma unroll
  for (int p = 0; p < 3; ++p) {
    int idx = p * 256 + tid;
    if (idx < 516) {
      int k = idx >> 2, pr = idx & 3;
      float2 h1 = Hraw[2 * pr][k], h2 = Hraw[2 * pr + 1][k];
      Wz[pr][__brev((unsigned)k) >> 24] = make_float2(h1.x - h2.y, h1.y + h2.x);
      if (k >= 1 && k <= 127)
        Wz[pr][__brev((unsigned)(256 - k)) >> 24] = make_float2(h1.x + h2.y, h2.x - h1.y);
    }
  }
  __syncthreads();
  int pr = tid >> 6, lane = tid & 63;
  #pragma unroll
  for (int len = 2; len <= 256; len <<= 1) {
    int half = len >> 1;
    float ang = 6.2831853071795864f / (float)len;
    #pragma unroll
    for (int s = 0; s < 2; ++s) {
      int bi = lane + 64 * s;
      int j = bi & (half - 1);
      int i0 = ((bi & ~(half - 1)) << 1) | j;
      int i1 = i0 + half;
      float sn, cs;
      __sincosf(ang * (float)j, &sn, &cs);
      float2 z0 = Wz[pr][i0], z1 = Wz[pr][i1];
      float2 t = make_float2(cs * z1.x - sn * z1.y, cs * z1.y + sn * z1.x);
      Wz[pr][i1] = make_float2(z0.x - t.x, z0.y - t.y);
      Wz[pr][i0] = make_float2(z0.x + t.x, z0.y + t.y);
    }
    __syncthreads();
  }
  const float inv = 1.f / 256.f;
  #pragma unroll
  for (int j = 0; j < 4; ++j) {
    int n = lane + 64 * j;
    float2 wv = Wz[pr][n];
    hb[(size_t)(m0 + 2 * pr) * N_ + n]     = f2bf(wv.x * inv);
    hb[(size_t)(m0 + 2 * pr + 1) * N_ + n] = f2bf(wv.y * inv);
  }
}

// ---------------- launch ----------------
extern "C" void kernel_launch(void* const* d_in, const int* in_sizes, int n_in,
                              void* d_out, int out_size, void* d_ws, size_t ws_size,
                              hipStream_t stream) {
  const float* x      = (const float*)d_in[0];
  const float* Wa_w   = (const float*)d_in[1];
  const float* Wa_b   = (const float*)d_in[2];
  const float* lg     = (const float*)d_in[3];
  const float* WB_w   = (const float*)d_in[4];
  const float* WB_b   = (const float*)d_in[5];
  const float* WC_w   = (const float*)d_in[6];
  const float* WC_b   = (const float*)d_in[7];
  const float* D_skip = (const float*)d_in[8];
  const float* ln_w   = (const float*)d_in[9];
  const float* ln_b   = (const float*)d_in[10];
  float* out = (float*)d_out;
  char* ws = (char*)d_ws;

  // Workspace layout (lifetime-overlapped):
  //   [0, 33.55MB): xn bf16 (early)  |  ah+uh float2 spectra (late)
  //   [33.55MB, 34.60MB): Wab bf16 (early, clobbered by uh tail later)
  //   [34.60MB, 35.13MB): WC bf16 (whole run)
  //   [35.13MB, 68.68MB): au_pre f32 (early) | h bf16 (late)
  ushort_t* xn  = (ushort_t*)(ws + 0);
  ushort_t* Wab = (ushort_t*)(ws + 33554432);
  ushort_t* WCb = (ushort_t*)(ws + 34603008);
  float*    au  = (float*)(ws + 35127296);
  ushort_t* hb  = (ushort_t*)(ws + 35127296);  // aliases au (dead by then)
  float2*   ah  = (float2*)(ws + 0);           // aliases xn (dead by then)
  float2*   uh  = (float2*)(ws + 16908288);    // h_hat written in place

  prep_w<<<3072, 256, 0, stream>>>(Wa_w, WB_w, WC_w, Wab, WCb);
  ln_kernel<<<M_, 256, 0, stream>>>(x, ln_w, ln_b, xn);
  gemm_bf16<false><<<512, 256, 0, stream>>>(xn, D_, Wab, D_, au, 512, D_, 4,
                                            nullptr, nullptr, nullptr);
  fft_fwd<<<M_ / 8, 512, 0, stream>>>(au, Wa_b, WB_b, lg, ah, uh);
  scan_kernel<<<B_ * KB_, 512, 0, stream>>>(ah, uh);
  ifft_kernel<<<M_ / 8, 256, 0, stream>>>(uh, hb);
  gemm_bf16<true><<<1024, 256, 0, stream>>>(hb, N_, WCb, N_, out, D_, N_, 8,
                                            WC_b, D_skip, x);
}

// Round 3
// 141.632 us; speedup vs baseline: 1.0924x; 1.0219x over previous
//
#include <hip/hip_runtime.h>

// CirculantSSMLayer on MI355X.
// Pipeline: LN -> bf16 MFMA GEMM (Wa|WB fused) -> packed real FFT256 (a+iu trick)
//           -> per-(b,k) block-scan over T -> packed inverse FFT -> bf16 MFMA GEMM + epilogue.
// R3: LDS twiddle tables (kill per-butterfly sincos), wave-shuffle scan (1 barrier),
//     barrier-free wave-per-row LN. GEMMs unchanged (m97 structure).

typedef unsigned short ushort_t;
typedef short s16x8 __attribute__((ext_vector_type(8)));
typedef float f32x4 __attribute__((ext_vector_type(4)));

#define B_ 4
#define T_ 4096
#define D_ 1024
#define N_ 256
#define KB_ 129
#define M_ (B_*T_)

__device__ __forceinline__ ushort_t f2bf(float f) {
  unsigned u = __float_as_uint(f);
  u = (u + 0x7FFFu + ((u >> 16) & 1u)) >> 16;
  return (ushort_t)u;
}
__device__ __forceinline__ float2 cmul(float2 a, float2 b) {
  return make_float2(a.x*b.x - a.y*b.y, a.x*b.y + a.y*b.x);
}
__device__ __forceinline__ float fast_tanh(float x) {
  // 1 - 2/(e^{2x}+1); saturates correctly via inf/0
  return 1.f - 2.f / (__expf(2.f * x) + 1.f);
}

typedef const __attribute__((address_space(1))) unsigned glb_u32;
typedef __attribute__((address_space(3))) unsigned lds_u32;
__device__ __forceinline__ void gload16(const void* g, void* l) {
  __builtin_amdgcn_global_load_lds((glb_u32*)g, (lds_u32*)l, 16, 0, 0);
}

// ---------------- weight prep: f32 -> bf16 ----------------
__global__ __launch_bounds__(256) void prep_w(const float* __restrict__ Wa,
    const float* __restrict__ WB, const float* __restrict__ WC,
    ushort_t* __restrict__ Wab, ushort_t* __restrict__ WCb) {
  int i = blockIdx.x * 256 + threadIdx.x;
  const int nab = 512 * 1024;
  if (i < nab) {
    float v = (i < 256 * 1024) ? Wa[i] : WB[i - 256 * 1024];
    Wab[i] = f2bf(v);
  } else {
    int j = i - nab;
    if (j < 1024 * 256) WCb[j] = f2bf(WC[j]);
  }
}

// ---------------- layernorm -> bf16: one wave per row, no barriers ----------------
__global__ __launch_bounds__(256) void ln_kernel(const float* __restrict__ x,
    const float* __restrict__ w, const float* __restrict__ bb,
    ushort_t* __restrict__ xn) {
  int tid = threadIdx.x, lane = tid & 63, wv = tid >> 6;
  int row = blockIdx.x * 4 + wv;
  const float4* xr = (const float4*)(x + (size_t)row * D_);
  float4 v[4];
  float s = 0.f, sq = 0.f;
  #pragma unroll
  for (int j = 0; j < 4; ++j) {
    v[j] = xr[lane + 64 * j];
    s  += v[j].x + v[j].y + v[j].z + v[j].w;
    sq += v[j].x*v[j].x + v[j].y*v[j].y + v[j].z*v[j].z + v[j].w*v[j].w;
  }
  #pragma unroll
  for (int off = 32; off >= 1; off >>= 1) {
    s  += __shfl_xor(s, off);
    sq += __shfl_xor(sq, off);
  }
  float mu  = s * (1.0f / D_);
  float var = sq * (1.0f / D_) - mu * mu;
  float rs  = rsqrtf(var + 1e-5f);
  const float4* w4 = (const float4*)w;
  const float4* b4 = (const float4*)bb;
  ushort4* o4 = (ushort4*)(xn + (size_t)row * D_);
  #pragma unroll
  for (int j = 0; j < 4; ++j) {
    float4 wv_ = w4[lane + 64 * j];
    float4 bv_ = b4[lane + 64 * j];
    ushort4 o;
    o.x = f2bf((v[j].x - mu) * rs * wv_.x + bv_.x);
    o.y = f2bf((v[j].y - mu) * rs * wv_.y + bv_.y);
    o.z = f2bf((v[j].z - mu) * rs * wv_.z + bv_.z);
    o.w = f2bf((v[j].w - mu) * rs * wv_.w + bv_.w);
    o4[lane + 64 * j] = o;
  }
}

// ---------------- bf16 MFMA GEMM: C[m][n] = sum_k A[m][k]*B[n][k] ----------------
// m97 structure: 128x128 tile, BK=32, 4 waves (2x2), 16x16x32 MFMA,
// linear LDS [128][32], global_load_lds width-16, 2 barriers per K-step.
template<bool EPI>
__global__ __launch_bounds__(256) void gemm_bf16(
    const ushort_t* __restrict__ A, int lda,
    const ushort_t* __restrict__ B, int ldb,
    float* __restrict__ C, int ldc,
    int K, int ntiles,
    const float* __restrict__ bias,
    const float* __restrict__ dskip,
    const float* __restrict__ xres) {
  __shared__ ushort_t Alds[128 * 32];
  __shared__ ushort_t Blds[128 * 32];
  int bid = blockIdx.x;
  int cpx = gridDim.x >> 3;
  bid = (bid & 7) * cpx + (bid >> 3);
  int mt = bid / ntiles, nt = bid % ntiles;
  int m0 = mt * 128, n0 = nt * 128;
  int tid = threadIdx.x;
  int lane = tid & 63, wid = tid >> 6;
  int wm = wid >> 1, wn = wid & 1;

  int srow = wid * 32 + (lane >> 2);
  int scol = (lane & 3) * 8;
  const ushort_t* gA0 = A + (size_t)(m0 + srow) * lda + scol;
  const ushort_t* gA1 = A + (size_t)(m0 + srow + 16) * lda + scol;
  const ushort_t* gB0 = B + (size_t)(n0 + srow) * ldb + scol;
  const ushort_t* gB1 = B + (size_t)(n0 + srow + 16) * ldb + scol;
  ushort_t* lA0 = &Alds[(wid * 32) * 32];
  ushort_t* lA1 = &Alds[(wid * 32 + 16) * 32];
  ushort_t* lB0 = &Blds[(wid * 32) * 32];
  ushort_t* lB1 = &Blds[(wid * 32 + 16) * 32];

  f32x4 acc[4][4] = {};
  int koff = (lane >> 4) * 8;
  int rbase = lane & 15;

  for (int k0 = 0; k0 < K; k0 += 32) {
    __syncthreads();
    gload16(gA0 + k0, lA0);
    gload16(gA1 + k0, lA1);
    gload16(gB0 + k0, lB0);
    gload16(gB1 + k0, lB1);
    __syncthreads();
    s16x8 af[4], bf[4];
    #pragma unroll
    for (int i = 0; i < 4; ++i) {
      af[i] = *reinterpret_cast<const s16x8*>(&Alds[(wm * 64 + i * 16 + rbase) * 32 + koff]);
      bf[i] = *reinterpret_cast<const s16x8*>(&Blds[(wn * 64 + i * 16 + rbase) * 32 + koff]);
    }
    #pragma unroll
    for (int i = 0; i < 4; ++i)
      #pragma unroll
      for (int j = 0; j < 4; ++j)
        acc[i][j] = __builtin_amdgcn_mfma_f32_16x16x32_bf16(af[i], bf[j], acc[i][j], 0, 0, 0);
  }

  int r0 = (lane >> 4) * 4, cc = lane & 15;
  #pragma unroll
  for (int i = 0; i < 4; ++i) {
    #pragma unroll
    for (int j = 0; j < 4; ++j) {
      int col = n0 + wn * 64 + j * 16 + cc;
      #pragma unroll
      for (int r = 0; r < 4; ++r) {
        int row = m0 + wm * 64 + i * 16 + r0 + r;
        float v = acc[i][j][r];
        if constexpr (EPI) v += bias[col] + dskip[col] * xres[(size_t)row * ldc + col];
        C[(size_t)row * ldc + col] = v;
      }
    }
  }
}

// ---------------- forward: bias+tanh+gate, packed FFT256, gate-by-magnitude ----------------
// Block: 512 threads = 8 rows (one wave each). z = a + i*u, one FFT serves both.
// Twiddles from a shared 128-entry table: stage `len` uses Tw[j << (8 - log2 len)].
__global__ __launch_bounds__(512) void fft_fwd(const float* __restrict__ au,
    const float* __restrict__ ba, const float* __restrict__ bu,
    const float* __restrict__ lg, float2* __restrict__ ah, float2* __restrict__ uh) {
  __shared__ float2 Z[8][256];
  __shared__ float2 Tw[128];
  int tid = threadIdx.x;
  int m0 = blockIdx.x * 8;
  int tg = tid >> 6, lane = tid & 63;
  if (tid < 128) {
    float sn, cs;
    __sincosf(-3.14159265358979f / 128.f * (float)tid, &sn, &cs);
    Tw[tid] = make_float2(cs, sn);
  }
  float gamma = 1.f / (1.f + __expf(-lg[0]));
  const float* row = au + (size_t)(m0 + tg) * (2 * N_);
  #pragma unroll
  for (int j = 0; j < 4; ++j) {
    int n = lane + 64 * j;
    float a = gamma * fast_tanh(row[n] + ba[n]);
    float u = row[N_ + n] + bu[n];
    Z[tg][__brev((unsigned)n) >> 24] = make_float2(a, u);
  }
  __syncthreads();
  #pragma unroll
  for (int st = 1; st <= 8; ++st) {
    int len = 1 << st, half = len >> 1, shift = 8 - st;
    #pragma unroll
    for (int s = 0; s < 2; ++s) {
      int bi = lane + 64 * s;
      int j = bi & (half - 1);
      int i0 = ((bi & ~(half - 1)) << 1) | j;
      int i1 = i0 + half;
      float2 tw = Tw[j << shift];
      float2 z0 = Z[tg][i0], z1 = Z[tg][i1];
      float2 t = cmul(tw, z1);
      Z[tg][i1] = make_float2(z0.x - t.x, z0.y - t.y);
      Z[tg][i0] = make_float2(z0.x + t.x, z0.y + t.y);
    }
    __syncthreads();
  }
  int b = m0 >> 12, tb = m0 & (T_ - 1);
  #pragma unroll
  for (int p = 0; p < 3; ++p) {
    int k = (tid >> 3) + p * 64;
    int tl = tid & 7;
    if (k <= 128) {
      float2 zk = Z[tl][k];
      float2 zn = Z[tl][(256 - k) & 255];
      float2 Af = make_float2(0.5f * (zk.x + zn.x), 0.5f * (zk.y - zn.y));
      float2 Uf = make_float2(0.5f * (zk.y + zn.y), -0.5f * (zk.x - zn.x));
      float mag = fmaxf(sqrtf(Af.x * Af.x + Af.y * Af.y), 1e-8f);
      float scl = 1.f / (1.f + __expf(-2.f * (1.f - mag)));
      Af.x *= scl; Af.y *= scl;
      size_t off = ((size_t)(b * KB_ + k)) * T_ + tb + tl;
      ah[off] = Af;
      uh[off] = Uf;
    }
  }
}

// ---------------- time scan: h_t = a_t*h_{t-1} + u_t per (b,k) chain ----------------
// One block per chain; 512 threads x 8 elems; wave shuffle-scan + 1 barrier.
__global__ __launch_bounds__(512) void scan_kernel(const float2* __restrict__ ah,
                                                   float2* __restrict__ uh) {
  __shared__ float4 wagg[8];
  int tid = threadIdx.x;
  int lane = tid & 63, wv = tid >> 6;
  size_t base = (size_t)blockIdx.x * T_;
  const float4* a4 = (const float4*)(ah + base);
  float4* u4 = (float4*)(uh + base);
  float4 Av[4], Uv[4];
  #pragma unroll
  for (int q = 0; q < 4; ++q) { Av[q] = a4[tid * 4 + q]; Uv[q] = u4[tid * 4 + q]; }
  // serial composite over this thread's 8 elements; composite (A,B): h_out = A*h_in + B
  float2 La[8], Lb[8];
  float2 ra = make_float2(1.f, 0.f), rb = make_float2(0.f, 0.f);
  #pragma unroll
  for (int e = 0; e < 8; ++e) {
    int q = e >> 1;
    float2 a, u;
    if (e & 1) { a = make_float2(Av[q].z, Av[q].w); u = make_float2(Uv[q].z, Uv[q].w); }
    else       { a = make_float2(Av[q].x, Av[q].y); u = make_float2(Uv[q].x, Uv[q].y); }
    float2 t = cmul(a, rb);
    rb = make_float2(t.x + u.x, t.y + u.y);
    ra = cmul(ra, a);
    La[e] = ra; Lb[e] = rb;
  }
  // wave-level inclusive scan (register shuffles, no LDS)
  #pragma unroll
  for (int off = 1; off < 64; off <<= 1) {
    float ax = __shfl_up(ra.x, off, 64), ay = __shfl_up(ra.y, off, 64);
    float bx = __shfl_up(rb.x, off, 64), by = __shfl_up(rb.y, off, 64);
    if (lane >= off) {
      float2 Ap = make_float2(ax, ay), Bp = make_float2(bx, by);
      float2 nB = cmul(ra, Bp);
      nB.x += rb.x; nB.y += rb.y;
      ra = cmul(Ap, ra);
      rb = nB;
    }
  }
  if (lane == 63) wagg[wv] = make_float4(ra.x, ra.y, rb.x, rb.y);
  __syncthreads();
  // incoming h for this wave: B of composite of all previous waves (h_{-1}=0)
  float2 Bw = make_float2(0.f, 0.f);
  for (int w0 = 0; w0 < wv; ++w0) {
    float4 g = wagg[w0];
    float2 gA = make_float2(g.x, g.y), gB = make_float2(g.z, g.w);
    Bw = cmul(gA, Bw);
    Bw.x += gB.x; Bw.y += gB.y;
  }
  // lane-exclusive composite = inclusive of lane-1
  float ax = __shfl_up(ra.x, 1, 64), ay = __shfl_up(ra.y, 1, 64);
  float bx = __shfl_up(rb.x, 1, 64), by = __shfl_up(rb.y, 1, 64);
  float2 Ae, Be;
  if (lane == 0) { Ae = make_float2(1.f, 0.f); Be = make_float2(0.f, 0.f); }
  else           { Ae = make_float2(ax, ay);   Be = make_float2(bx, by);   }
  float2 Pb = cmul(Ae, Bw);
  Pb.x += Be.x; Pb.y += Be.y;
  #pragma unroll
  for (int q = 0; q < 4; ++q) {
    float2 h0 = cmul(La[2 * q], Pb);
    h0.x += Lb[2 * q].x; h0.y += Lb[2 * q].y;
    float2 h1 = cmul(La[2 * q + 1], Pb);
    h1.x += Lb[2 * q + 1].x; h1.y += Lb[2 * q + 1].y;
    u4[tid * 4 + q] = make_float4(h0.x, h0.y, h1.x, h1.y);
  }
}

// ---------------- inverse FFT: 2 real rows per complex transform -> h bf16 ----------------
// Block: 256 threads = 8 rows = 4 transforms (one wave each).
__global__ __launch_bounds__(256) void ifft_kernel(const float2* __restrict__ hh,
                                                   ushort_t* __restrict__ hb) {
  __shared__ float2 Hraw[8][132];
  __shared__ float2 Wz[4][256];
  __shared__ float2 Tw[128];
  int tid = threadIdx.x;
  int m0 = blockIdx.x * 8;
  int b = m0 >> 12, tb = m0 & (T_ - 1);
  if (tid < 128) {
    float sn, cs;
    __sincosf(3.14159265358979f / 128.f * (float)tid, &sn, &cs);
    Tw[tid] = make_float2(cs, sn);
  }
  #pragma unroll
  for (int p = 0; p < 5; ++p) {
    int k = p * 32 + (tid >> 3), tl = tid & 7;
    if (k <= 128) Hraw[tl][k] = hh[((size_t)(b * KB_ + k)) * T_ + tb + tl];
  }
  __syncthreads();
  #pragma unroll
  for (int p = 0; p < 3; ++p) {
    int idx = p * 256 + tid;
    if (idx < 516) {
      int k = idx >> 2, pr = idx & 3;
      float2 h1 = Hraw[2 * pr][k], h2 = Hraw[2 * pr + 1][k];
      Wz[pr][__brev((unsigned)k) >> 24] = make_float2(h1.x - h2.y, h1.y + h2.x);
      if (k >= 1 && k <= 127)
        Wz[pr][__brev((unsigned)(256 - k)) >> 24] = make_float2(h1.x + h2.y, h2.x - h1.y);
    }
  }
  __syncthreads();
  int pr = tid >> 6, lane = tid & 63;
  #pragma unroll
  for (int st = 1; st <= 8; ++st) {
    int len = 1 << st, half = len >> 1, shift = 8 - st;
    #pragma unroll
    for (int s = 0; s < 2; ++s) {
      int bi = lane + 64 * s;
      int j = bi & (half - 1);
      int i0 = ((bi & ~(half - 1)) << 1) | j;
      int i1 = i0 + half;
      float2 tw = Tw[j << shift];
      float2 z0 = Wz[pr][i0], z1 = Wz[pr][i1];
      float2 t = cmul(tw, z1);
      Wz[pr][i1] = make_float2(z0.x - t.x, z0.y - t.y);
      Wz[pr][i0] = make_float2(z0.x + t.x, z0.y + t.y);
    }
    __syncthreads();
  }
  const float inv = 1.f / 256.f;
  #pragma unroll
  for (int j = 0; j < 4; ++j) {
    int n = lane + 64 * j;
    float2 wv = Wz[pr][n];
    hb[(size_t)(m0 + 2 * pr) * N_ + n]     = f2bf(wv.x * inv);
    hb[(size_t)(m0 + 2 * pr + 1) * N_ + n] = f2bf(wv.y * inv);
  }
}

// ---------------- launch ----------------
extern "C" void kernel_launch(void* const* d_in, const int* in_sizes, int n_in,
                              void* d_out, int out_size, void* d_ws, size_t ws_size,
                              hipStream_t stream) {
  const float* x      = (const float*)d_in[0];
  const float* Wa_w   = (const float*)d_in[1];
  const float* Wa_b   = (const float*)d_in[2];
  const float* lg     = (const float*)d_in[3];
  const float* WB_w   = (const float*)d_in[4];
  const float* WB_b   = (const float*)d_in[5];
  const float* WC_w   = (const float*)d_in[6];
  const float* WC_b   = (const float*)d_in[7];
  const float* D_skip = (const float*)d_in[8];
  const float* ln_w   = (const float*)d_in[9];
  const float* ln_b   = (const float*)d_in[10];
  float* out = (float*)d_out;
  char* ws = (char*)d_ws;

  ushort_t* xn  = (ushort_t*)(ws + 0);
  ushort_t* Wab = (ushort_t*)(ws + 33554432);
  ushort_t* WCb = (ushort_t*)(ws + 34603008);
  float*    au  = (float*)(ws + 35127296);
  ushort_t* hb  = (ushort_t*)(ws + 35127296);  // aliases au (dead by then)
  float2*   ah  = (float2*)(ws + 0);           // aliases xn (dead by then)
  float2*   uh  = (float2*)(ws + 16908288);    // h_hat written in place

  prep_w<<<3072, 256, 0, stream>>>(Wa_w, WB_w, WC_w, Wab, WCb);
  ln_kernel<<<M_ / 4, 256, 0, stream>>>(x, ln_w, ln_b, xn);
  gemm_bf16<false><<<512, 256, 0, stream>>>(xn, D_, Wab, D_, au, 512, D_, 4,
                                            nullptr, nullptr, nullptr);
  fft_fwd<<<M_ / 8, 512, 0, stream>>>(au, Wa_b, WB_b, lg, ah, uh);
  scan_kernel<<<B_ * KB_, 512, 0, stream>>>(ah, uh);
  ifft_kernel<<<M_ / 8, 256, 0, stream>>>(uh, hb);
  gemm_bf16<true><<<1024, 256, 0, stream>>>(hb, N_, WCb, N_, out, D_, N_, 8,
                                            WC_b, D_skip, x);
}

// Round 4
// 129.262 us; speedup vs baseline: 1.1969x; 1.0957x over previous
//
#include <hip/hip_runtime.h>

// CirculantSSMLayer on MI355X.
// Pipeline: LN(+weight-prep) -> bf16 MFMA GEMM (Wa|WB fused) -> packed real FFT256
//           -> per-(b,k) block-scan over T -> packed inverse FFT -> bf16 MFMA GEMM + epilogue.
// R4: gemm1 BN=64 (grid 1024 = 4 blocks/CU; m97 needs >=4 for barrier-drain hiding),
//     prep_w fused into ln dispatch, XOR bank-swizzle on FFT/IFFT LDS indices.

typedef unsigned short ushort_t;
typedef short s16x8 __attribute__((ext_vector_type(8)));
typedef float f32x4 __attribute__((ext_vector_type(4)));

#define B_ 4
#define T_ 4096
#define D_ 1024
#define N_ 256
#define KB_ 129
#define M_ (B_*T_)

// LDS bank swizzle for float2 arrays: XOR bits 4-5 into bits 1-2 (involution).
#define SWZ(i) ((i) ^ (((i) >> 3) & 6))

__device__ __forceinline__ ushort_t f2bf(float f) {
  unsigned u = __float_as_uint(f);
  u = (u + 0x7FFFu + ((u >> 16) & 1u)) >> 16;
  return (ushort_t)u;
}
__device__ __forceinline__ float2 cmul(float2 a, float2 b) {
  return make_float2(a.x*b.x - a.y*b.y, a.x*b.y + a.y*b.x);
}
__device__ __forceinline__ float fast_tanh(float x) {
  return 1.f - 2.f / (__expf(2.f * x) + 1.f);
}

typedef const __attribute__((address_space(1))) unsigned glb_u32;
typedef __attribute__((address_space(3))) unsigned lds_u32;
__device__ __forceinline__ void gload16(const void* g, void* l) {
  __builtin_amdgcn_global_load_lds((glb_u32*)g, (lds_u32*)l, 16, 0, 0);
}

// ---------------- layernorm (blocks 0..4095) + weight f32->bf16 (blocks 4096..4863) ----
__global__ __launch_bounds__(256) void ln_prep_kernel(const float* __restrict__ x,
    const float* __restrict__ w, const float* __restrict__ bb,
    ushort_t* __restrict__ xn,
    const float* __restrict__ Wa, const float* __restrict__ WB,
    const float* __restrict__ WC, ushort_t* __restrict__ Wab,
    ushort_t* __restrict__ WCb) {
  int tid = threadIdx.x;
  if (blockIdx.x >= 4096) {
    int i4 = ((blockIdx.x - 4096) * 256 + tid) * 4;
    float4 v;
    ushort_t* dst;
    if (i4 < 262144)        { v = *(const float4*)(Wa + i4);          dst = Wab + i4; }
    else if (i4 < 524288)   { v = *(const float4*)(WB + i4 - 262144); dst = Wab + i4; }
    else                    { v = *(const float4*)(WC + i4 - 524288); dst = WCb + i4 - 524288; }
    ushort4 o;
    o.x = f2bf(v.x); o.y = f2bf(v.y); o.z = f2bf(v.z); o.w = f2bf(v.w);
    *(ushort4*)dst = o;
    return;
  }
  int lane = tid & 63, wv = tid >> 6;
  int row = blockIdx.x * 4 + wv;
  const float4* xr = (const float4*)(x + (size_t)row * D_);
  float4 v[4];
  float s = 0.f, sq = 0.f;
  #pragma unroll
  for (int j = 0; j < 4; ++j) {
    v[j] = xr[lane + 64 * j];
    s  += v[j].x + v[j].y + v[j].z + v[j].w;
    sq += v[j].x*v[j].x + v[j].y*v[j].y + v[j].z*v[j].z + v[j].w*v[j].w;
  }
  #pragma unroll
  for (int off = 32; off >= 1; off >>= 1) {
    s  += __shfl_xor(s, off);
    sq += __shfl_xor(sq, off);
  }
  float mu  = s * (1.0f / D_);
  float var = sq * (1.0f / D_) - mu * mu;
  float rs  = rsqrtf(var + 1e-5f);
  const float4* w4 = (const float4*)w;
  const float4* b4 = (const float4*)bb;
  ushort4* o4 = (ushort4*)(xn + (size_t)row * D_);
  #pragma unroll
  for (int j = 0; j < 4; ++j) {
    float4 wv_ = w4[lane + 64 * j];
    float4 bv_ = b4[lane + 64 * j];
    ushort4 o;
    o.x = f2bf((v[j].x - mu) * rs * wv_.x + bv_.x);
    o.y = f2bf((v[j].y - mu) * rs * wv_.y + bv_.y);
    o.z = f2bf((v[j].z - mu) * rs * wv_.z + bv_.z);
    o.w = f2bf((v[j].w - mu) * rs * wv_.w + bv_.w);
    o4[lane + 64 * j] = o;
  }
}

// ---------------- bf16 MFMA GEMM: C[m][n] = sum_k A[m][k]*B[n][k] ----------------
// m97 structure: BM=128 x BN tile, BK=32, 4 waves (2x2), 16x16x32 MFMA,
// linear LDS, global_load_lds width-16, 2 barriers per K-step.
// BN=64 -> grid doubles (4 blocks/CU) for barrier-drain hiding; BN=128 classic.
template<bool EPI, int BN>
__global__ __launch_bounds__(256) void gemm_bf16(
    const ushort_t* __restrict__ A, int lda,
    const ushort_t* __restrict__ B, int ldb,
    float* __restrict__ C, int ldc,
    int K, int ntiles,
    const float* __restrict__ bias,
    const float* __restrict__ dskip,
    const float* __restrict__ xres) {
  constexpr int NF = BN / 32;          // N fragments per wave
  __shared__ ushort_t Alds[128 * 32];
  __shared__ ushort_t Blds[BN * 32];
  int bid = blockIdx.x;
  int cpx = gridDim.x >> 3;
  bid = (bid & 7) * cpx + (bid >> 3);
  int mt = bid / ntiles, nt = bid % ntiles;
  int m0 = mt * 128, n0 = nt * BN;
  int tid = threadIdx.x;
  int lane = tid & 63, wid = tid >> 6;
  int wm = wid >> 1, wn = wid & 1;

  int lrow = lane >> 2;
  int scol = (lane & 3) * 8;
  const ushort_t* gA0 = A + (size_t)(m0 + wid * 32 + lrow) * lda + scol;
  const ushort_t* gA1 = gA0 + (size_t)16 * lda;
  ushort_t* lA0 = &Alds[(wid * 32) * 32];
  ushort_t* lA1 = lA0 + 16 * 32;
  constexpr int BROWS = BN / 4;        // B rows staged per wave
  const ushort_t* gB0 = B + (size_t)(n0 + wid * BROWS + lrow) * ldb + scol;
  ushort_t* lB0 = &Blds[(wid * BROWS) * 32];

  f32x4 acc[4][NF] = {};
  int koff = (lane >> 4) * 8;
  int rbase = lane & 15;

  for (int k0 = 0; k0 < K; k0 += 32) {
    __syncthreads();
    gload16(gA0 + k0, lA0);
    gload16(gA1 + k0, lA1);
    gload16(gB0 + k0, lB0);
    if constexpr (BN == 128) gload16(gB0 + (size_t)16 * ldb + k0, lB0 + 16 * 32);
    __syncthreads();
    s16x8 af[4], bf[NF];
    #pragma unroll
    for (int i = 0; i < 4; ++i)
      af[i] = *reinterpret_cast<const s16x8*>(&Alds[(wm * 64 + i * 16 + rbase) * 32 + koff]);
    #pragma unroll
    for (int j = 0; j < NF; ++j)
      bf[j] = *reinterpret_cast<const s16x8*>(&Blds[(wn * (BN / 2) + j * 16 + rbase) * 32 + koff]);
    #pragma unroll
    for (int i = 0; i < 4; ++i)
      #pragma unroll
      for (int j = 0; j < NF; ++j)
        acc[i][j] = __builtin_amdgcn_mfma_f32_16x16x32_bf16(af[i], bf[j], acc[i][j], 0, 0, 0);
  }

  int r0 = (lane >> 4) * 4, cc = lane & 15;
  #pragma unroll
  for (int i = 0; i < 4; ++i) {
    #pragma unroll
    for (int j = 0; j < NF; ++j) {
      int col = n0 + wn * (BN / 2) + j * 16 + cc;
      #pragma unroll
      for (int r = 0; r < 4; ++r) {
        int row = m0 + wm * 64 + i * 16 + r0 + r;
        float v = acc[i][j][r];
        if constexpr (EPI) v += bias[col] + dskip[col] * xres[(size_t)row * ldc + col];
        C[(size_t)row * ldc + col] = v;
      }
    }
  }
}

// ---------------- forward: bias+tanh+gate, packed FFT256, gate-by-magnitude ----------------
// Block: 512 threads = 8 rows (one wave each). z = a + i*u, one FFT serves both.
__global__ __launch_bounds__(512) void fft_fwd(const float* __restrict__ au,
    const float* __restrict__ ba, const float* __restrict__ bu,
    const float* __restrict__ lg, float2* __restrict__ ah, float2* __restrict__ uh) {
  __shared__ float2 Z[8][256];
  __shared__ float2 Tw[128];
  int tid = threadIdx.x;
  int m0 = blockIdx.x * 8;
  int tg = tid >> 6, lane = tid & 63;
  if (tid < 128) {
    float sn, cs;
    __sincosf(-3.14159265358979f / 128.f * (float)tid, &sn, &cs);
    Tw[SWZ(tid) & 127] = make_float2(cs, sn);
  }
  float gamma = 1.f / (1.f + __expf(-lg[0]));
  const float* row = au + (size_t)(m0 + tg) * (2 * N_);
  #pragma unroll
  for (int j = 0; j < 4; ++j) {
    int n = lane + 64 * j;
    float a = gamma * fast_tanh(row[n] + ba[n]);
    float u = row[N_ + n] + bu[n];
    Z[tg][SWZ(__brev((unsigned)n) >> 24)] = make_float2(a, u);
  }
  __syncthreads();
  #pragma unroll
  for (int st = 1; st <= 8; ++st) {
    int half = 1 << (st - 1), shift = 8 - st;
    #pragma unroll
    for (int s = 0; s < 2; ++s) {
      int bi = lane + 64 * s;
      int j = bi & (half - 1);
      int i0 = ((bi & ~(half - 1)) << 1) | j;
      int i1 = i0 + half;
      float2 tw = Tw[SWZ(j << shift) & 127];
      float2 z0 = Z[tg][SWZ(i0)], z1 = Z[tg][SWZ(i1)];
      float2 t = cmul(tw, z1);
      Z[tg][SWZ(i1)] = make_float2(z0.x - t.x, z0.y - t.y);
      Z[tg][SWZ(i0)] = make_float2(z0.x + t.x, z0.y + t.y);
    }
    __syncthreads();
  }
  int b = m0 >> 12, tb = m0 & (T_ - 1);
  #pragma unroll
  for (int p = 0; p < 3; ++p) {
    int k = (tid >> 3) + p * 64;
    int tl = tid & 7;
    if (k <= 128) {
      float2 zk = Z[tl][SWZ(k)];
      float2 zn = Z[tl][SWZ((256 - k) & 255)];
      float2 Af = make_float2(0.5f * (zk.x + zn.x), 0.5f * (zk.y - zn.y));
      float2 Uf = make_float2(0.5f * (zk.y + zn.y), -0.5f * (zk.x - zn.x));
      float mag = fmaxf(sqrtf(Af.x * Af.x + Af.y * Af.y), 1e-8f);
      float scl = 1.f / (1.f + __expf(-2.f * (1.f - mag)));
      Af.x *= scl; Af.y *= scl;
      size_t off = ((size_t)(b * KB_ + k)) * T_ + tb + tl;
      ah[off] = Af;
      uh[off] = Uf;
    }
  }
}

// ---------------- time scan: h_t = a_t*h_{t-1} + u_t per (b,k) chain ----------------
__global__ __launch_bounds__(512) void scan_kernel(const float2* __restrict__ ah,
                                                   float2* __restrict__ uh) {
  __shared__ float4 wagg[8];
  int tid = threadIdx.x;
  int lane = tid & 63, wv = tid >> 6;
  size_t base = (size_t)blockIdx.x * T_;
  const float4* a4 = (const float4*)(ah + base);
  float4* u4 = (float4*)(uh + base);
  float4 Av[4], Uv[4];
  #pragma unroll
  for (int q = 0; q < 4; ++q) { Av[q] = a4[tid * 4 + q]; Uv[q] = u4[tid * 4 + q]; }
  float2 La[8], Lb[8];
  float2 ra = make_float2(1.f, 0.f), rb = make_float2(0.f, 0.f);
  #pragma unroll
  for (int e = 0; e < 8; ++e) {
    int q = e >> 1;
    float2 a, u;
    if (e & 1) { a = make_float2(Av[q].z, Av[q].w); u = make_float2(Uv[q].z, Uv[q].w); }
    else       { a = make_float2(Av[q].x, Av[q].y); u = make_float2(Uv[q].x, Uv[q].y); }
    float2 t = cmul(a, rb);
    rb = make_float2(t.x + u.x, t.y + u.y);
    ra = cmul(ra, a);
    La[e] = ra; Lb[e] = rb;
  }
  #pragma unroll
  for (int off = 1; off < 64; off <<= 1) {
    float ax = __shfl_up(ra.x, off, 64), ay = __shfl_up(ra.y, off, 64);
    float bx = __shfl_up(rb.x, off, 64), by = __shfl_up(rb.y, off, 64);
    if (lane >= off) {
      float2 Ap = make_float2(ax, ay), Bp = make_float2(bx, by);
      float2 nB = cmul(ra, Bp);
      nB.x += rb.x; nB.y += rb.y;
      ra = cmul(Ap, ra);
      rb = nB;
    }
  }
  if (lane == 63) wagg[wv] = make_float4(ra.x, ra.y, rb.x, rb.y);
  __syncthreads();
  float2 Bw = make_float2(0.f, 0.f);
  for (int w0 = 0; w0 < wv; ++w0) {
    float4 g = wagg[w0];
    float2 gA = make_float2(g.x, g.y), gB = make_float2(g.z, g.w);
    Bw = cmul(gA, Bw);
    Bw.x += gB.x; Bw.y += gB.y;
  }
  float ax = __shfl_up(ra.x, 1, 64), ay = __shfl_up(ra.y, 1, 64);
  float bx = __shfl_up(rb.x, 1, 64), by = __shfl_up(rb.y, 1, 64);
  float2 Ae, Be;
  if (lane == 0) { Ae = make_float2(1.f, 0.f); Be = make_float2(0.f, 0.f); }
  else           { Ae = make_float2(ax, ay);   Be = make_float2(bx, by);   }
  float2 Pb = cmul(Ae, Bw);
  Pb.x += Be.x; Pb.y += Be.y;
  #pragma unroll
  for (int q = 0; q < 4; ++q) {
    float2 h0 = cmul(La[2 * q], Pb);
    h0.x += Lb[2 * q].x; h0.y += Lb[2 * q].y;
    float2 h1 = cmul(La[2 * q + 1], Pb);
    h1.x += Lb[2 * q + 1].x; h1.y += Lb[2 * q + 1].y;
    u4[tid * 4 + q] = make_float4(h0.x, h0.y, h1.x, h1.y);
  }
}

// ---------------- inverse FFT: 2 real rows per complex transform -> h bf16 ----------------
__global__ __launch_bounds__(256) void ifft_kernel(const float2* __restrict__ hh,
                                                   ushort_t* __restrict__ hb) {
  __shared__ float2 Hraw[8][132];
  __shared__ float2 Wz[4][256];
  __shared__ float2 Tw[128];
  int tid = threadIdx.x;
  int m0 = blockIdx.x * 8;
  int b = m0 >> 12, tb = m0 & (T_ - 1);
  if (tid < 128) {
    float sn, cs;
    __sincosf(3.14159265358979f / 128.f * (float)tid, &sn, &cs);
    Tw[SWZ(tid) & 127] = make_float2(cs, sn);
  }
  #pragma unroll
  for (int p = 0; p < 5; ++p) {
    int k = p * 32 + (tid >> 3), tl = tid & 7;
    if (k <= 128) Hraw[tl][k] = hh[((size_t)(b * KB_ + k)) * T_ + tb + tl];
  }
  __syncthreads();
  #pragma unroll
  for (int p = 0; p < 3; ++p) {
    int idx = p * 256 + tid;
    if (idx < 516) {
      int k = idx >> 2, pr = idx & 3;
      float2 h1 = Hraw[2 * pr][k], h2 = Hraw[2 * pr + 1][k];
      Wz[pr][SWZ(__brev((unsigned)k) >> 24)] = make_float2(h1.x - h2.y, h1.y + h2.x);
      if (k >= 1 && k <= 127)
        Wz[pr][SWZ(__brev((unsigned)(256 - k)) >> 24)] = make_float2(h1.x + h2.y, h2.x - h1.y);
    }
  }
  __syncthreads();
  int pr = tid >> 6, lane = tid & 63;
  #pragma unroll
  for (int st = 1; st <= 8; ++st) {
    int half = 1 << (st - 1), shift = 8 - st;
    #pragma unroll
    for (int s = 0; s < 2; ++s) {
      int bi = lane + 64 * s;
      int j = bi & (half - 1);
      int i0 = ((bi & ~(half - 1)) << 1) | j;
      int i1 = i0 + half;
      float2 tw = Tw[SWZ(j << shift) & 127];
      float2 z0 = Wz[pr][SWZ(i0)], z1 = Wz[pr][SWZ(i1)];
      float2 t = cmul(tw, z1);
      Wz[pr][SWZ(i1)] = make_float2(z0.x - t.x, z0.y - t.y);
      Wz[pr][SWZ(i0)] = make_float2(z0.x + t.x, z0.y + t.y);
    }
    __syncthreads();
  }
  const float inv = 1.f / 256.f;
  #pragma unroll
  for (int j = 0; j < 4; ++j) {
    int n = lane + 64 * j;
    float2 wv = Wz[pr][SWZ(n)];
    hb[(size_t)(m0 + 2 * pr) * N_ + n]     = f2bf(wv.x * inv);
    hb[(size_t)(m0 + 2 * pr + 1) * N_ + n] = f2bf(wv.y * inv);
  }
}

// ---------------- launch ----------------
extern "C" void kernel_launch(void* const* d_in, const int* in_sizes, int n_in,
                              void* d_out, int out_size, void* d_ws, size_t ws_size,
                              hipStream_t stream) {
  const float* x      = (const float*)d_in[0];
  const float* Wa_w   = (const float*)d_in[1];
  const float* Wa_b   = (const float*)d_in[2];
  const float* lg     = (const float*)d_in[3];
  const float* WB_w   = (const float*)d_in[4];
  const float* WB_b   = (const float*)d_in[5];
  const float* WC_w   = (const float*)d_in[6];
  const float* WC_b   = (const float*)d_in[7];
  const float* D_skip = (const float*)d_in[8];
  const float* ln_w   = (const float*)d_in[9];
  const float* ln_b   = (const float*)d_in[10];
  float* out = (float*)d_out;
  char* ws = (char*)d_ws;

  ushort_t* xn  = (ushort_t*)(ws + 0);
  ushort_t* Wab = (ushort_t*)(ws + 33554432);
  ushort_t* WCb = (ushort_t*)(ws + 34603008);
  float*    au  = (float*)(ws + 35127296);
  ushort_t* hb  = (ushort_t*)(ws + 35127296);  // aliases au (dead by then)
  float2*   ah  = (float2*)(ws + 0);           // aliases xn (dead by then)
  float2*   uh  = (float2*)(ws + 16908288);    // h_hat written in place

  ln_prep_kernel<<<4864, 256, 0, stream>>>(x, ln_w, ln_b, xn,
                                           Wa_w, WB_w, WC_w, Wab, WCb);
  gemm_bf16<false, 64><<<1024, 256, 0, stream>>>(xn, D_, Wab, D_, au, 512, D_, 8,
                                                 nullptr, nullptr, nullptr);
  fft_fwd<<<M_ / 8, 512, 0, stream>>>(au, Wa_b, WB_b, lg, ah, uh);
  scan_kernel<<<B_ * KB_, 512, 0, stream>>>(ah, uh);
  ifft_kernel<<<M_ / 8, 256, 0, stream>>>(uh, hb);
  gemm_bf16<true, 128><<<1024, 256, 0, stream>>>(hb, N_, WCb, N_, out, D_, N_, 8,
                                                 WC_b, D_skip, x);
}

// Round 5
// 121.245 us; speedup vs baseline: 1.2761x; 1.0661x over previous
//
#include <hip/hip_runtime.h>

// CirculantSSMLayer on MI355X.
// Pipeline: LN(+weight-prep) -> bf16 MFMA GEMM (Wa|WB fused) -> packed real FFT256
//           -> per-(b,k) block-scan over T -> packed inverse FFT -> bf16 MFMA GEMM + epilogue.
// R5: fp16 at-rest storage for au and ah/uh spectra (compute stays f32 in-register).
//     Halves traffic of gemm1-out, fft-out, scan r/w, ifft-in (~67 MB saved).

typedef unsigned short ushort_t;
typedef short s16x8 __attribute__((ext_vector_type(8)));
typedef float f32x4 __attribute__((ext_vector_type(4)));
typedef _Float16 f16x8 __attribute__((ext_vector_type(8)));
typedef _Float16 f16x2 __attribute__((ext_vector_type(2)));

#define B_ 4
#define T_ 4096
#define D_ 1024
#define N_ 256
#define KB_ 129
#define M_ (B_*T_)

// LDS bank swizzle for float2 arrays: XOR bits 4-5 into bits 1-2 (involution).
#define SWZ(i) ((i) ^ (((i) >> 3) & 6))

__device__ __forceinline__ ushort_t f2bf(float f) {
  unsigned u = __float_as_uint(f);
  u = (u + 0x7FFFu + ((u >> 16) & 1u)) >> 16;
  return (ushort_t)u;
}
__device__ __forceinline__ float2 cmul(float2 a, float2 b) {
  return make_float2(a.x*b.x - a.y*b.y, a.x*b.y + a.y*b.x);
}
__device__ __forceinline__ float fast_tanh(float x) {
  return 1.f - 2.f / (__expf(2.f * x) + 1.f);
}

typedef const __attribute__((address_space(1))) unsigned glb_u32;
typedef __attribute__((address_space(3))) unsigned lds_u32;
__device__ __forceinline__ void gload16(const void* g, void* l) {
  __builtin_amdgcn_global_load_lds((glb_u32*)g, (lds_u32*)l, 16, 0, 0);
}

// ---------------- layernorm (blocks 0..4095) + weight f32->bf16 (blocks 4096..4863) ----
__global__ __launch_bounds__(256) void ln_prep_kernel(const float* __restrict__ x,
    const float* __restrict__ w, const float* __restrict__ bb,
    ushort_t* __restrict__ xn,
    const float* __restrict__ Wa, const float* __restrict__ WB,
    const float* __restrict__ WC, ushort_t* __restrict__ Wab,
    ushort_t* __restrict__ WCb) {
  int tid = threadIdx.x;
  if (blockIdx.x >= 4096) {
    int i4 = ((blockIdx.x - 4096) * 256 + tid) * 4;
    float4 v;
    ushort_t* dst;
    if (i4 < 262144)        { v = *(const float4*)(Wa + i4);          dst = Wab + i4; }
    else if (i4 < 524288)   { v = *(const float4*)(WB + i4 - 262144); dst = Wab + i4; }
    else                    { v = *(const float4*)(WC + i4 - 524288); dst = WCb + i4 - 524288; }
    ushort4 o;
    o.x = f2bf(v.x); o.y = f2bf(v.y); o.z = f2bf(v.z); o.w = f2bf(v.w);
    *(ushort4*)dst = o;
    return;
  }
  int lane = tid & 63, wv = tid >> 6;
  int row = blockIdx.x * 4 + wv;
  const float4* xr = (const float4*)(x + (size_t)row * D_);
  float4 v[4];
  float s = 0.f, sq = 0.f;
  #pragma unroll
  for (int j = 0; j < 4; ++j) {
    v[j] = xr[lane + 64 * j];
    s  += v[j].x + v[j].y + v[j].z + v[j].w;
    sq += v[j].x*v[j].x + v[j].y*v[j].y + v[j].z*v[j].z + v[j].w*v[j].w;
  }
  #pragma unroll
  for (int off = 32; off >= 1; off >>= 1) {
    s  += __shfl_xor(s, off);
    sq += __shfl_xor(sq, off);
  }
  float mu  = s * (1.0f / D_);
  float var = sq * (1.0f / D_) - mu * mu;
  float rs  = rsqrtf(var + 1e-5f);
  const float4* w4 = (const float4*)w;
  const float4* b4 = (const float4*)bb;
  ushort4* o4 = (ushort4*)(xn + (size_t)row * D_);
  #pragma unroll
  for (int j = 0; j < 4; ++j) {
    float4 wv_ = w4[lane + 64 * j];
    float4 bv_ = b4[lane + 64 * j];
    ushort4 o;
    o.x = f2bf((v[j].x - mu) * rs * wv_.x + bv_.x);
    o.y = f2bf((v[j].y - mu) * rs * wv_.y + bv_.y);
    o.z = f2bf((v[j].z - mu) * rs * wv_.z + bv_.z);
    o.w = f2bf((v[j].w - mu) * rs * wv_.w + bv_.w);
    o4[lane + 64 * j] = o;
  }
}

// ---------------- bf16 MFMA GEMM: C[m][n] = sum_k A[m][k]*B[n][k] ----------------
// m97 structure: BM=128 x BN tile, BK=32, 4 waves (2x2), 16x16x32 MFMA,
// linear LDS, global_load_lds width-16, 2 barriers per K-step.
// HOUT: write _Float16 output instead of f32.
template<bool EPI, int BN, bool HOUT>
__global__ __launch_bounds__(256) void gemm_bf16(
    const ushort_t* __restrict__ A, int lda,
    const ushort_t* __restrict__ B, int ldb,
    void* __restrict__ Cv, int ldc,
    int K, int ntiles,
    const float* __restrict__ bias,
    const float* __restrict__ dskip,
    const float* __restrict__ xres) {
  constexpr int NF = BN / 32;          // N fragments per wave
  __shared__ ushort_t Alds[128 * 32];
  __shared__ ushort_t Blds[BN * 32];
  int bid = blockIdx.x;
  int cpx = gridDim.x >> 3;
  bid = (bid & 7) * cpx + (bid >> 3);
  int mt = bid / ntiles, nt = bid % ntiles;
  int m0 = mt * 128, n0 = nt * BN;
  int tid = threadIdx.x;
  int lane = tid & 63, wid = tid >> 6;
  int wm = wid >> 1, wn = wid & 1;

  int lrow = lane >> 2;
  int scol = (lane & 3) * 8;
  const ushort_t* gA0 = A + (size_t)(m0 + wid * 32 + lrow) * lda + scol;
  const ushort_t* gA1 = gA0 + (size_t)16 * lda;
  ushort_t* lA0 = &Alds[(wid * 32) * 32];
  ushort_t* lA1 = lA0 + 16 * 32;
  constexpr int BROWS = BN / 4;        // B rows staged per wave
  const ushort_t* gB0 = B + (size_t)(n0 + wid * BROWS + lrow) * ldb + scol;
  ushort_t* lB0 = &Blds[(wid * BROWS) * 32];

  f32x4 acc[4][NF] = {};
  int koff = (lane >> 4) * 8;
  int rbase = lane & 15;

  for (int k0 = 0; k0 < K; k0 += 32) {
    __syncthreads();
    gload16(gA0 + k0, lA0);
    gload16(gA1 + k0, lA1);
    gload16(gB0 + k0, lB0);
    if constexpr (BN == 128) gload16(gB0 + (size_t)16 * ldb + k0, lB0 + 16 * 32);
    __syncthreads();
    s16x8 af[4], bf[NF];
    #pragma unroll
    for (int i = 0; i < 4; ++i)
      af[i] = *reinterpret_cast<const s16x8*>(&Alds[(wm * 64 + i * 16 + rbase) * 32 + koff]);
    #pragma unroll
    for (int j = 0; j < NF; ++j)
      bf[j] = *reinterpret_cast<const s16x8*>(&Blds[(wn * (BN / 2) + j * 16 + rbase) * 32 + koff]);
    #pragma unroll
    for (int i = 0; i < 4; ++i)
      #pragma unroll
      for (int j = 0; j < NF; ++j)
        acc[i][j] = __builtin_amdgcn_mfma_f32_16x16x32_bf16(af[i], bf[j], acc[i][j], 0, 0, 0);
  }

  int r0 = (lane >> 4) * 4, cc = lane & 15;
  #pragma unroll
  for (int i = 0; i < 4; ++i) {
    #pragma unroll
    for (int j = 0; j < NF; ++j) {
      int col = n0 + wn * (BN / 2) + j * 16 + cc;
      #pragma unroll
      for (int r = 0; r < 4; ++r) {
        int row = m0 + wm * 64 + i * 16 + r0 + r;
        float v = acc[i][j][r];
        if constexpr (EPI) v += bias[col] + dskip[col] * xres[(size_t)row * ldc + col];
        if constexpr (HOUT) ((_Float16*)Cv)[(size_t)row * ldc + col] = (_Float16)v;
        else                ((float*)Cv)[(size_t)row * ldc + col] = v;
      }
    }
  }
}

// ---------------- forward: bias+tanh+gate, packed FFT256, gate-by-magnitude ----------------
// Block: 512 threads = 8 rows (one wave each). z = a + i*u, one FFT serves both.
// au input fp16; ah/uh outputs fp16 pairs.
__global__ __launch_bounds__(512) void fft_fwd(const _Float16* __restrict__ au,
    const float* __restrict__ ba, const float* __restrict__ bu,
    const float* __restrict__ lg, _Float16* __restrict__ ah, _Float16* __restrict__ uh) {
  __shared__ float2 Z[8][256];
  __shared__ float2 Tw[128];
  int tid = threadIdx.x;
  int m0 = blockIdx.x * 8;
  int tg = tid >> 6, lane = tid & 63;
  if (tid < 128) {
    float sn, cs;
    __sincosf(-3.14159265358979f / 128.f * (float)tid, &sn, &cs);
    Tw[SWZ(tid)] = make_float2(cs, sn);
  }
  float gamma = 1.f / (1.f + __expf(-lg[0]));
  const _Float16* row = au + (size_t)(m0 + tg) * (2 * N_);
  #pragma unroll
  for (int j = 0; j < 4; ++j) {
    int n = lane + 64 * j;
    float a = gamma * fast_tanh((float)row[n] + ba[n]);
    float u = (float)row[N_ + n] + bu[n];
    Z[tg][SWZ(__brev((unsigned)n) >> 24)] = make_float2(a, u);
  }
  __syncthreads();
  #pragma unroll
  for (int st = 1; st <= 8; ++st) {
    int half = 1 << (st - 1), shift = 8 - st;
    #pragma unroll
    for (int s = 0; s < 2; ++s) {
      int bi = lane + 64 * s;
      int j = bi & (half - 1);
      int i0 = ((bi & ~(half - 1)) << 1) | j;
      int i1 = i0 + half;
      float2 tw = Tw[SWZ(j << shift)];
      float2 z0 = Z[tg][SWZ(i0)], z1 = Z[tg][SWZ(i1)];
      float2 t = cmul(tw, z1);
      Z[tg][SWZ(i1)] = make_float2(z0.x - t.x, z0.y - t.y);
      Z[tg][SWZ(i0)] = make_float2(z0.x + t.x, z0.y + t.y);
    }
    __syncthreads();
  }
  int b = m0 >> 12, tb = m0 & (T_ - 1);
  #pragma unroll
  for (int p = 0; p < 3; ++p) {
    int k = (tid >> 3) + p * 64;
    int tl = tid & 7;
    if (k <= 128) {
      float2 zk = Z[tl][SWZ(k)];
      float2 zn = Z[tl][SWZ((256 - k) & 255)];
      float2 Af = make_float2(0.5f * (zk.x + zn.x), 0.5f * (zk.y - zn.y));
      float2 Uf = make_float2(0.5f * (zk.y + zn.y), -0.5f * (zk.x - zn.x));
      float mag = fmaxf(sqrtf(Af.x * Af.x + Af.y * Af.y), 1e-8f);
      float scl = 1.f / (1.f + __expf(-2.f * (1.f - mag)));
      Af.x *= scl; Af.y *= scl;
      size_t off2 = (((size_t)(b * KB_ + k)) * T_ + tb + tl) * 2;
      f16x2 av; av[0] = (_Float16)Af.x; av[1] = (_Float16)Af.y;
      f16x2 uv; uv[0] = (_Float16)Uf.x; uv[1] = (_Float16)Uf.y;
      *(f16x2*)(ah + off2) = av;
      *(f16x2*)(uh + off2) = uv;
    }
  }
}

// ---------------- time scan: h_t = a_t*h_{t-1} + u_t per (b,k) chain ----------------
// fp16 at-rest, f32 compute. 512 threads x 8 complex each; shuffle-scan + 1 barrier.
__global__ __launch_bounds__(512) void scan_kernel(const _Float16* __restrict__ ah,
                                                   _Float16* __restrict__ uh) {
  __shared__ float4 wagg[8];
  int tid = threadIdx.x;
  int lane = tid & 63, wv = tid >> 6;
  size_t base = (size_t)blockIdx.x * T_ * 2;
  const f16x8* a8 = (const f16x8*)(ah + base);
  f16x8* u8 = (f16x8*)(uh + base);
  f16x8 Av[2], Uv[2];
  #pragma unroll
  for (int q = 0; q < 2; ++q) { Av[q] = a8[tid * 2 + q]; Uv[q] = u8[tid * 2 + q]; }
  float2 La[8], Lb[8];
  float2 ra = make_float2(1.f, 0.f), rb = make_float2(0.f, 0.f);
  #pragma unroll
  for (int e = 0; e < 8; ++e) {
    const int q = e >> 2, i = (e & 3) * 2;
    float2 a = make_float2((float)Av[q][i], (float)Av[q][i + 1]);
    float2 u = make_float2((float)Uv[q][i], (float)Uv[q][i + 1]);
    float2 t = cmul(a, rb);
    rb = make_float2(t.x + u.x, t.y + u.y);
    ra = cmul(ra, a);
    La[e] = ra; Lb[e] = rb;
  }
  #pragma unroll
  for (int off = 1; off < 64; off <<= 1) {
    float ax = __shfl_up(ra.x, off, 64), ay = __shfl_up(ra.y, off, 64);
    float bx = __shfl_up(rb.x, off, 64), by = __shfl_up(rb.y, off, 64);
    if (lane >= off) {
      float2 Ap = make_float2(ax, ay), Bp = make_float2(bx, by);
      float2 nB = cmul(ra, Bp);
      nB.x += rb.x; nB.y += rb.y;
      ra = cmul(Ap, ra);
      rb = nB;
    }
  }
  if (lane == 63) wagg[wv] = make_float4(ra.x, ra.y, rb.x, rb.y);
  __syncthreads();
  float2 Bw = make_float2(0.f, 0.f);
  for (int w0 = 0; w0 < wv; ++w0) {
    float4 g = wagg[w0];
    float2 gA = make_float2(g.x, g.y), gB = make_float2(g.z, g.w);
    Bw = cmul(gA, Bw);
    Bw.x += gB.x; Bw.y += gB.y;
  }
  float ax = __shfl_up(ra.x, 1, 64), ay = __shfl_up(ra.y, 1, 64);
  float bx = __shfl_up(rb.x, 1, 64), by = __shfl_up(rb.y, 1, 64);
  float2 Ae, Be;
  if (lane == 0) { Ae = make_float2(1.f, 0.f); Be = make_float2(0.f, 0.f); }
  else           { Ae = make_float2(ax, ay);   Be = make_float2(bx, by);   }
  float2 Pb = cmul(Ae, Bw);
  Pb.x += Be.x; Pb.y += Be.y;
  #pragma unroll
  for (int q = 0; q < 2; ++q) {
    f16x8 o;
    #pragma unroll
    for (int e2 = 0; e2 < 4; ++e2) {
      const int e = q * 4 + e2;
      float2 h = cmul(La[e], Pb);
      h.x += Lb[e].x; h.y += Lb[e].y;
      o[e2 * 2]     = (_Float16)h.x;
      o[e2 * 2 + 1] = (_Float16)h.y;
    }
    u8[tid * 2 + q] = o;
  }
}

// ---------------- inverse FFT: 2 real rows per complex transform -> h bf16 ----------------
__global__ __launch_bounds__(256) void ifft_kernel(const _Float16* __restrict__ hh,
                                                   ushort_t* __restrict__ hb) {
  __shared__ float2 Hraw[8][132];
  __shared__ float2 Wz[4][256];
  __shared__ float2 Tw[128];
  int tid = threadIdx.x;
  int m0 = blockIdx.x * 8;
  int b = m0 >> 12, tb = m0 & (T_ - 1);
  if (tid < 128) {
    float sn, cs;
    __sincosf(3.14159265358979f / 128.f * (float)tid, &sn, &cs);
    Tw[SWZ(tid)] = make_float2(cs, sn);
  }
  #pragma unroll
  for (int p = 0; p < 5; ++p) {
    int k = p * 32 + (tid >> 3), tl = tid & 7;
    if (k <= 128) {
      f16x2 hv = *(const f16x2*)(hh + (((size_t)(b * KB_ + k)) * T_ + tb + tl) * 2);
      Hraw[tl][k] = make_float2((float)hv[0], (float)hv[1]);
    }
  }
  __syncthreads();
  #pragma unroll
  for (int p = 0; p < 3; ++p) {
    int idx = p * 256 + tid;
    if (idx < 516) {
      int k = idx >> 2, pr = idx & 3;
      float2 h1 = Hraw[2 * pr][k], h2 = Hraw[2 * pr + 1][k];
      Wz[pr][SWZ(__brev((unsigned)k) >> 24)] = make_float2(h1.x - h2.y, h1.y + h2.x);
      if (k >= 1 && k <= 127)
        Wz[pr][SWZ(__brev((unsigned)(256 - k)) >> 24)] = make_float2(h1.x + h2.y, h2.x - h1.y);
    }
  }
  __syncthreads();
  int pr = tid >> 6, lane = tid & 63;
  #pragma unroll
  for (int st = 1; st <= 8; ++st) {
    int half = 1 << (st - 1), shift = 8 - st;
    #pragma unroll
    for (int s = 0; s < 2; ++s) {
      int bi = lane + 64 * s;
      int j = bi & (half - 1);
      int i0 = ((bi & ~(half - 1)) << 1) | j;
      int i1 = i0 + half;
      float2 tw = Tw[SWZ(j << shift)];
      float2 z0 = Wz[pr][SWZ(i0)], z1 = Wz[pr][SWZ(i1)];
      float2 t = cmul(tw, z1);
      Wz[pr][SWZ(i1)] = make_float2(z0.x - t.x, z0.y - t.y);
      Wz[pr][SWZ(i0)] = make_float2(z0.x + t.x, z0.y + t.y);
    }
    __syncthreads();
  }
  const float inv = 1.f / 256.f;
  #pragma unroll
  for (int j = 0; j < 4; ++j) {
    int n = lane + 64 * j;
    float2 wv = Wz[pr][SWZ(n)];
    hb[(size_t)(m0 + 2 * pr) * N_ + n]     = f2bf(wv.x * inv);
    hb[(size_t)(m0 + 2 * pr + 1) * N_ + n] = f2bf(wv.y * inv);
  }
}

// ---------------- launch ----------------
extern "C" void kernel_launch(void* const* d_in, const int* in_sizes, int n_in,
                              void* d_out, int out_size, void* d_ws, size_t ws_size,
                              hipStream_t stream) {
  const float* x      = (const float*)d_in[0];
  const float* Wa_w   = (const float*)d_in[1];
  const float* Wa_b   = (const float*)d_in[2];
  const float* lg     = (const float*)d_in[3];
  const float* WB_w   = (const float*)d_in[4];
  const float* WB_b   = (const float*)d_in[5];
  const float* WC_w   = (const float*)d_in[6];
  const float* WC_b   = (const float*)d_in[7];
  const float* D_skip = (const float*)d_in[8];
  const float* ln_w   = (const float*)d_in[9];
  const float* ln_b   = (const float*)d_in[10];
  float* out = (float*)d_out;
  char* ws = (char*)d_ws;

  // Workspace (lifetime-overlapped):
  //   [0, 33.55MB): xn bf16 (early) | ah fp16 spectra 8.45MB + uh fp16 at 16.9MB (late)
  //   [33.55MB, 34.60MB): Wab bf16 (dead after gemm1)
  //   [34.60MB, 35.13MB): WCb bf16 (whole run)
  //   [35.13MB, +16.8MB): au fp16 (dead after fft) | hb bf16 8.4MB (late)
  ushort_t*  xn  = (ushort_t*)(ws + 0);
  ushort_t*  Wab = (ushort_t*)(ws + 33554432);
  ushort_t*  WCb = (ushort_t*)(ws + 34603008);
  _Float16*  au  = (_Float16*)(ws + 35127296);
  ushort_t*  hb  = (ushort_t*)(ws + 35127296);   // aliases au (dead by then)
  _Float16*  ah  = (_Float16*)(ws + 0);          // aliases xn (dead by then)
  _Float16*  uh  = (_Float16*)(ws + 16908288);   // h_hat written in place

  ln_prep_kernel<<<4864, 256, 0, stream>>>(x, ln_w, ln_b, xn,
                                           Wa_w, WB_w, WC_w, Wab, WCb);
  gemm_bf16<false, 64, true><<<1024, 256, 0, stream>>>(xn, D_, Wab, D_, au, 512,
                                                       D_, 8, nullptr, nullptr, nullptr);
  fft_fwd<<<M_ / 8, 512, 0, stream>>>(au, Wa_b, WB_b, lg, ah, uh);
  scan_kernel<<<B_ * KB_, 512, 0, stream>>>(ah, uh);
  ifft_kernel<<<M_ / 8, 256, 0, stream>>>(uh, hb);
  gemm_bf16<true, 128, false><<<1024, 256, 0, stream>>>(hb, N_, WCb, N_, out, D_,
                                                        N_, 8, WC_b, D_skip, x);
}

// Round 6
// 113.287 us; speedup vs baseline: 1.3657x; 1.0702x over previous
//
#include <hip/hip_runtime.h>

// CirculantSSMLayer on MI355X.
// Pipeline: LN(+weight-prep) -> bf16 MFMA GEMM (Wa|WB fused) -> packed real FFT256
//           -> per-(b,k) block-scan over T -> packed inverse FFT -> bf16 MFMA GEMM + epilogue.
// R6: GEMM BK=64 (halves barrier-drain count). LDS rows are 128B now, so fragment
//     reads use a granule XOR swizzle (linear LDS dest + pre-swizzled global source,
//     rule: both-sides-or-neither with global_load_lds).

typedef unsigned short ushort_t;
typedef short s16x8 __attribute__((ext_vector_type(8)));
typedef float f32x4 __attribute__((ext_vector_type(4)));
typedef _Float16 f16x8 __attribute__((ext_vector_type(8)));
typedef _Float16 f16x2 __attribute__((ext_vector_type(2)));

#define B_ 4
#define T_ 4096
#define D_ 1024
#define N_ 256
#define KB_ 129
#define M_ (B_*T_)

// LDS bank swizzle for float2 arrays: XOR bits 4-5 into bits 1-2 (involution).
#define SWZ(i) ((i) ^ (((i) >> 3) & 6))

__device__ __forceinline__ ushort_t f2bf(float f) {
  unsigned u = __float_as_uint(f);
  u = (u + 0x7FFFu + ((u >> 16) & 1u)) >> 16;
  return (ushort_t)u;
}
__device__ __forceinline__ float2 cmul(float2 a, float2 b) {
  return make_float2(a.x*b.x - a.y*b.y, a.x*b.y + a.y*b.x);
}
__device__ __forceinline__ float fast_tanh(float x) {
  return 1.f - 2.f / (__expf(2.f * x) + 1.f);
}

typedef const __attribute__((address_space(1))) unsigned glb_u32;
typedef __attribute__((address_space(3))) unsigned lds_u32;
__device__ __forceinline__ void gload16(const void* g, void* l) {
  __builtin_amdgcn_global_load_lds((glb_u32*)g, (lds_u32*)l, 16, 0, 0);
}

// ---------------- layernorm (blocks 0..4095) + weight f32->bf16 (blocks 4096..4863) ----
__global__ __launch_bounds__(256) void ln_prep_kernel(const float* __restrict__ x,
    const float* __restrict__ w, const float* __restrict__ bb,
    ushort_t* __restrict__ xn,
    const float* __restrict__ Wa, const float* __restrict__ WB,
    const float* __restrict__ WC, ushort_t* __restrict__ Wab,
    ushort_t* __restrict__ WCb) {
  int tid = threadIdx.x;
  if (blockIdx.x >= 4096) {
    int i4 = ((blockIdx.x - 4096) * 256 + tid) * 4;
    float4 v;
    ushort_t* dst;
    if (i4 < 262144)        { v = *(const float4*)(Wa + i4);          dst = Wab + i4; }
    else if (i4 < 524288)   { v = *(const float4*)(WB + i4 - 262144); dst = Wab + i4; }
    else                    { v = *(const float4*)(WC + i4 - 524288); dst = WCb + i4 - 524288; }
    ushort4 o;
    o.x = f2bf(v.x); o.y = f2bf(v.y); o.z = f2bf(v.z); o.w = f2bf(v.w);
    *(ushort4*)dst = o;
    return;
  }
  int lane = tid & 63, wv = tid >> 6;
  int row = blockIdx.x * 4 + wv;
  const float4* xr = (const float4*)(x + (size_t)row * D_);
  float4 v[4];
  float s = 0.f, sq = 0.f;
  #pragma unroll
  for (int j = 0; j < 4; ++j) {
    v[j] = xr[lane + 64 * j];
    s  += v[j].x + v[j].y + v[j].z + v[j].w;
    sq += v[j].x*v[j].x + v[j].y*v[j].y + v[j].z*v[j].z + v[j].w*v[j].w;
  }
  #pragma unroll
  for (int off = 32; off >= 1; off >>= 1) {
    s  += __shfl_xor(s, off);
    sq += __shfl_xor(sq, off);
  }
  float mu  = s * (1.0f / D_);
  float var = sq * (1.0f / D_) - mu * mu;
  float rs  = rsqrtf(var + 1e-5f);
  const float4* w4 = (const float4*)w;
  const float4* b4 = (const float4*)bb;
  ushort4* o4 = (ushort4*)(xn + (size_t)row * D_);
  #pragma unroll
  for (int j = 0; j < 4; ++j) {
    float4 wv_ = w4[lane + 64 * j];
    float4 bv_ = b4[lane + 64 * j];
    ushort4 o;
    o.x = f2bf((v[j].x - mu) * rs * wv_.x + bv_.x);
    o.y = f2bf((v[j].y - mu) * rs * wv_.y + bv_.y);
    o.z = f2bf((v[j].z - mu) * rs * wv_.z + bv_.z);
    o.w = f2bf((v[j].w - mu) * rs * wv_.w + bv_.w);
    o4[lane + 64 * j] = o;
  }
}

// ---------------- bf16 MFMA GEMM: C[m][n] = sum_k A[m][k]*B[n][k] ----------------
// BM=128 x BN tile, BK=64, 4 waves (2x2), 16x16x32 MFMA, global_load_lds width-16,
// 2 barriers per K-step (16 steps for K=1024, 4 for K=256).
// LDS rows = 64 shorts (128B): granule-XOR swizzle, slot = gk ^ (row&7);
// staged via pre-swizzled per-lane GLOBAL source (LDS dest stays linear).
template<bool EPI, int BN, bool HOUT>
__global__ __launch_bounds__(256) void gemm_bf16(
    const ushort_t* __restrict__ A, int lda,
    const ushort_t* __restrict__ B, int ldb,
    void* __restrict__ Cv, int ldc,
    int K, int ntiles,
    const float* __restrict__ bias,
    const float* __restrict__ dskip,
    const float* __restrict__ xres) {
  constexpr int NF = BN / 32;          // N fragments per wave
  __shared__ ushort_t Alds[128 * 64];
  __shared__ ushort_t Blds[BN * 64];
  int bid = blockIdx.x;
  int cpx = gridDim.x >> 3;
  bid = (bid & 7) * cpx + (bid >> 3);
  int mt = bid / ntiles, nt = bid % ntiles;
  int m0 = mt * 128, n0 = nt * BN;
  int tid = threadIdx.x;
  int lane = tid & 63, wid = tid >> 6;
  int wm = wid >> 1, wn = wid & 1;

  // staging: each gload16 call stages 8 rows x 64 shorts (1KB). lane ->
  // LDS slot (row = lane>>3, granule = lane&7); source data granule is
  // XOR-swizzled so that read slot = gk ^ (row&7).
  int lr8 = lane >> 3;                  // 0..7 (and row&7 for every staged row)
  int gd  = (lane & 7) ^ lr8;           // source data granule
  const ushort_t* gA = A + (size_t)(m0 + wid * 32 + lr8) * lda + gd * 8;
  ushort_t* lA = &Alds[(wid * 32) * 64];
  constexpr int BROWS = BN / 4;         // B rows staged per wave (16 or 32)
  const ushort_t* gB = B + (size_t)(n0 + wid * BROWS + lr8) * ldb + gd * 8;
  ushort_t* lB = &Blds[(wid * BROWS) * 64];

  f32x4 acc[4][NF] = {};
  int rbase = lane & 15;
  int rb7 = lane & 7;
  int gk0 = lane >> 4;                  // k-granule 0..3 (+4 for kk=1)

  for (int k0 = 0; k0 < K; k0 += 64) {
    __syncthreads();
    #pragma unroll
    for (int c = 0; c < 4; ++c)
      gload16(gA + (size_t)(c * 8) * lda + k0, lA + c * 8 * 64);
    #pragma unroll
    for (int c = 0; c < BROWS / 8; ++c)
      gload16(gB + (size_t)(c * 8) * ldb + k0, lB + c * 8 * 64);
    __syncthreads();
    #pragma unroll
    for (int kk = 0; kk < 2; ++kk) {
      int sl = ((gk0 + kk * 4) ^ rb7) * 8;
      s16x8 af[4], bf[NF];
      #pragma unroll
      for (int i = 0; i < 4; ++i)
        af[i] = *reinterpret_cast<const s16x8*>(&Alds[(wm * 64 + i * 16 + rbase) * 64 + sl]);
      #pragma unroll
      for (int j = 0; j < NF; ++j)
        bf[j] = *reinterpret_cast<const s16x8*>(&Blds[(wn * (BN / 2) + j * 16 + rbase) * 64 + sl]);
      #pragma unroll
      for (int i = 0; i < 4; ++i)
        #pragma unroll
        for (int j = 0; j < NF; ++j)
          acc[i][j] = __builtin_amdgcn_mfma_f32_16x16x32_bf16(af[i], bf[j], acc[i][j], 0, 0, 0);
    }
  }

  int r0 = (lane >> 4) * 4, cc = lane & 15;
  #pragma unroll
  for (int i = 0; i < 4; ++i) {
    #pragma unroll
    for (int j = 0; j < NF; ++j) {
      int col = n0 + wn * (BN / 2) + j * 16 + cc;
      #pragma unroll
      for (int r = 0; r < 4; ++r) {
        int row = m0 + wm * 64 + i * 16 + r0 + r;
        float v = acc[i][j][r];
        if constexpr (EPI) v += bias[col] + dskip[col] * xres[(size_t)row * ldc + col];
        if constexpr (HOUT) ((_Float16*)Cv)[(size_t)row * ldc + col] = (_Float16)v;
        else                ((float*)Cv)[(size_t)row * ldc + col] = v;
      }
    }
  }
}

// ---------------- forward: bias+tanh+gate, packed FFT256, gate-by-magnitude ----------------
// Block: 512 threads = 8 rows (one wave each). z = a + i*u, one FFT serves both.
// au input fp16; ah/uh outputs fp16 pairs.
__global__ __launch_bounds__(512) void fft_fwd(const _Float16* __restrict__ au,
    const float* __restrict__ ba, const float* __restrict__ bu,
    const float* __restrict__ lg, _Float16* __restrict__ ah, _Float16* __restrict__ uh) {
  __shared__ float2 Z[8][256];
  __shared__ float2 Tw[128];
  int tid = threadIdx.x;
  int m0 = blockIdx.x * 8;
  int tg = tid >> 6, lane = tid & 63;
  if (tid < 128) {
    float sn, cs;
    __sincosf(-3.14159265358979f / 128.f * (float)tid, &sn, &cs);
    Tw[SWZ(tid)] = make_float2(cs, sn);
  }
  float gamma = 1.f / (1.f + __expf(-lg[0]));
  const _Float16* row = au + (size_t)(m0 + tg) * (2 * N_);
  #pragma unroll
  for (int j = 0; j < 4; ++j) {
    int n = lane + 64 * j;
    float a = gamma * fast_tanh((float)row[n] + ba[n]);
    float u = (float)row[N_ + n] + bu[n];
    Z[tg][SWZ(__brev((unsigned)n) >> 24)] = make_float2(a, u);
  }
  __syncthreads();
  #pragma unroll
  for (int st = 1; st <= 8; ++st) {
    int half = 1 << (st - 1), shift = 8 - st;
    #pragma unroll
    for (int s = 0; s < 2; ++s) {
      int bi = lane + 64 * s;
      int j = bi & (half - 1);
      int i0 = ((bi & ~(half - 1)) << 1) | j;
      int i1 = i0 + half;
      float2 tw = Tw[SWZ(j << shift)];
      float2 z0 = Z[tg][SWZ(i0)], z1 = Z[tg][SWZ(i1)];
      float2 t = cmul(tw, z1);
      Z[tg][SWZ(i1)] = make_float2(z0.x - t.x, z0.y - t.y);
      Z[tg][SWZ(i0)] = make_float2(z0.x + t.x, z0.y + t.y);
    }
    __syncthreads();
  }
  int b = m0 >> 12, tb = m0 & (T_ - 1);
  #pragma unroll
  for (int p = 0; p < 3; ++p) {
    int k = (tid >> 3) + p * 64;
    int tl = tid & 7;
    if (k <= 128) {
      float2 zk = Z[tl][SWZ(k)];
      float2 zn = Z[tl][SWZ((256 - k) & 255)];
      float2 Af = make_float2(0.5f * (zk.x + zn.x), 0.5f * (zk.y - zn.y));
      float2 Uf = make_float2(0.5f * (zk.y + zn.y), -0.5f * (zk.x - zn.x));
      float mag = fmaxf(sqrtf(Af.x * Af.x + Af.y * Af.y), 1e-8f);
      float scl = 1.f / (1.f + __expf(-2.f * (1.f - mag)));
      Af.x *= scl; Af.y *= scl;
      size_t off2 = (((size_t)(b * KB_ + k)) * T_ + tb + tl) * 2;
      f16x2 av; av[0] = (_Float16)Af.x; av[1] = (_Float16)Af.y;
      f16x2 uv; uv[0] = (_Float16)Uf.x; uv[1] = (_Float16)Uf.y;
      *(f16x2*)(ah + off2) = av;
      *(f16x2*)(uh + off2) = uv;
    }
  }
}

// ---------------- time scan: h_t = a_t*h_{t-1} + u_t per (b,k) chain ----------------
// fp16 at-rest, f32 compute. 512 threads x 8 complex each; shuffle-scan + 1 barrier.
__global__ __launch_bounds__(512) void scan_kernel(const _Float16* __restrict__ ah,
                                                   _Float16* __restrict__ uh) {
  __shared__ float4 wagg[8];
  int tid = threadIdx.x;
  int lane = tid & 63, wv = tid >> 6;
  size_t base = (size_t)blockIdx.x * T_ * 2;
  const f16x8* a8 = (const f16x8*)(ah + base);
  f16x8* u8 = (f16x8*)(uh + base);
  f16x8 Av[2], Uv[2];
  #pragma unroll
  for (int q = 0; q < 2; ++q) { Av[q] = a8[tid * 2 + q]; Uv[q] = u8[tid * 2 + q]; }
  float2 La[8], Lb[8];
  float2 ra = make_float2(1.f, 0.f), rb = make_float2(0.f, 0.f);
  #pragma unroll
  for (int e = 0; e < 8; ++e) {
    const int q = e >> 2, i = (e & 3) * 2;
    float2 a = make_float2((float)Av[q][i], (float)Av[q][i + 1]);
    float2 u = make_float2((float)Uv[q][i], (float)Uv[q][i + 1]);
    float2 t = cmul(a, rb);
    rb = make_float2(t.x + u.x, t.y + u.y);
    ra = cmul(ra, a);
    La[e] = ra; Lb[e] = rb;
  }
  #pragma unroll
  for (int off = 1; off < 64; off <<= 1) {
    float ax = __shfl_up(ra.x, off, 64), ay = __shfl_up(ra.y, off, 64);
    float bx = __shfl_up(rb.x, off, 64), by = __shfl_up(rb.y, off, 64);
    if (lane >= off) {
      float2 Ap = make_float2(ax, ay), Bp = make_float2(bx, by);
      float2 nB = cmul(ra, Bp);
      nB.x += rb.x; nB.y += rb.y;
      ra = cmul(Ap, ra);
      rb = nB;
    }
  }
  if (lane == 63) wagg[wv] = make_float4(ra.x, ra.y, rb.x, rb.y);
  __syncthreads();
  float2 Bw = make_float2(0.f, 0.f);
  for (int w0 = 0; w0 < wv; ++w0) {
    float4 g = wagg[w0];
    float2 gA = make_float2(g.x, g.y), gB = make_float2(g.z, g.w);
    Bw = cmul(gA, Bw);
    Bw.x += gB.x; Bw.y += gB.y;
  }
  float ax = __shfl_up(ra.x, 1, 64), ay = __shfl_up(ra.y, 1, 64);
  float bx = __shfl_up(rb.x, 1, 64), by = __shfl_up(rb.y, 1, 64);
  float2 Ae, Be;
  if (lane == 0) { Ae = make_float2(1.f, 0.f); Be = make_float2(0.f, 0.f); }
  else           { Ae = make_float2(ax, ay);   Be = make_float2(bx, by);   }
  float2 Pb = cmul(Ae, Bw);
  Pb.x += Be.x; Pb.y += Be.y;
  #pragma unroll
  for (int q = 0; q < 2; ++q) {
    f16x8 o;
    #pragma unroll
    for (int e2 = 0; e2 < 4; ++e2) {
      const int e = q * 4 + e2;
      float2 h = cmul(La[e], Pb);
      h.x += Lb[e].x; h.y += Lb[e].y;
      o[e2 * 2]     = (_Float16)h.x;
      o[e2 * 2 + 1] = (_Float16)h.y;
    }
    u8[tid * 2 + q] = o;
  }
}

// ---------------- inverse FFT: 2 real rows per complex transform -> h bf16 ----------------
__global__ __launch_bounds__(256) void ifft_kernel(const _Float16* __restrict__ hh,
                                                   ushort_t* __restrict__ hb) {
  __shared__ float2 Hraw[8][132];
  __shared__ float2 Wz[4][256];
  __shared__ float2 Tw[128];
  int tid = threadIdx.x;
  int m0 = blockIdx.x * 8;
  int b = m0 >> 12, tb = m0 & (T_ - 1);
  if (tid < 128) {
    float sn, cs;
    __sincosf(3.14159265358979f / 128.f * (float)tid, &sn, &cs);
    Tw[SWZ(tid)] = make_float2(cs, sn);
  }
  #pragma unroll
  for (int p = 0; p < 5; ++p) {
    int k = p * 32 + (tid >> 3), tl = tid & 7;
    if (k <= 128) {
      f16x2 hv = *(const f16x2*)(hh + (((size_t)(b * KB_ + k)) * T_ + tb + tl) * 2);
      Hraw[tl][k] = make_float2((float)hv[0], (float)hv[1]);
    }
  }
  __syncthreads();
  #pragma unroll
  for (int p = 0; p < 3; ++p) {
    int idx = p * 256 + tid;
    if (idx < 516) {
      int k = idx >> 2, pr = idx & 3;
      float2 h1 = Hraw[2 * pr][k], h2 = Hraw[2 * pr + 1][k];
      Wz[pr][SWZ(__brev((unsigned)k) >> 24)] = make_float2(h1.x - h2.y, h1.y + h2.x);
      if (k >= 1 && k <= 127)
        Wz[pr][SWZ(__brev((unsigned)(256 - k)) >> 24)] = make_float2(h1.x + h2.y, h2.x - h1.y);
    }
  }
  __syncthreads();
  int pr = tid >> 6, lane = tid & 63;
  #pragma unroll
  for (int st = 1; st <= 8; ++st) {
    int half = 1 << (st - 1), shift = 8 - st;
    #pragma unroll
    for (int s = 0; s < 2; ++s) {
      int bi = lane + 64 * s;
      int j = bi & (half - 1);
      int i0 = ((bi & ~(half - 1)) << 1) | j;
      int i1 = i0 + half;
      float2 tw = Tw[SWZ(j << shift)];
      float2 z0 = Wz[pr][SWZ(i0)], z1 = Wz[pr][SWZ(i1)];
      float2 t = cmul(tw, z1);
      Wz[pr][SWZ(i1)] = make_float2(z0.x - t.x, z0.y - t.y);
      Wz[pr][SWZ(i0)] = make_float2(z0.x + t.x, z0.y + t.y);
    }
    __syncthreads();
  }
  const float inv = 1.f / 256.f;
  #pragma unroll
  for (int j = 0; j < 4; ++j) {
    int n = lane + 64 * j;
    float2 wv = Wz[pr][SWZ(n)];
    hb[(size_t)(m0 + 2 * pr) * N_ + n]     = f2bf(wv.x * inv);
    hb[(size_t)(m0 + 2 * pr + 1) * N_ + n] = f2bf(wv.y * inv);
  }
}

// ---------------- launch ----------------
extern "C" void kernel_launch(void* const* d_in, const int* in_sizes, int n_in,
                              void* d_out, int out_size, void* d_ws, size_t ws_size,
                              hipStream_t stream) {
  const float* x      = (const float*)d_in[0];
  const float* Wa_w   = (const float*)d_in[1];
  const float* Wa_b   = (const float*)d_in[2];
  const float* lg     = (const float*)d_in[3];
  const float* WB_w   = (const float*)d_in[4];
  const float* WB_b   = (const float*)d_in[5];
  const float* WC_w   = (const float*)d_in[6];
  const float* WC_b   = (const float*)d_in[7];
  const float* D_skip = (const float*)d_in[8];
  const float* ln_w   = (const float*)d_in[9];
  const float* ln_b   = (const float*)d_in[10];
  float* out = (float*)d_out;
  char* ws = (char*)d_ws;

  // Workspace (lifetime-overlapped):
  //   [0, 33.55MB): xn bf16 (early) | ah fp16 spectra 8.45MB + uh fp16 at 16.9MB (late)
  //   [33.55MB, 34.60MB): Wab bf16 (dead after gemm1)
  //   [34.60MB, 35.13MB): WCb bf16 (whole run)
  //   [35.13MB, +16.8MB): au fp16 (dead after fft) | hb bf16 8.4MB (late)
  ushort_t*  xn  = (ushort_t*)(ws + 0);
  ushort_t*  Wab = (ushort_t*)(ws + 33554432);
  ushort_t*  WCb = (ushort_t*)(ws + 34603008);
  _Float16*  au  = (_Float16*)(ws + 35127296);
  ushort_t*  hb  = (ushort_t*)(ws + 35127296);   // aliases au (dead by then)
  _Float16*  ah  = (_Float16*)(ws + 0);          // aliases xn (dead by then)
  _Float16*  uh  = (_Float16*)(ws + 16908288);   // h_hat written in place

  ln_prep_kernel<<<4864, 256, 0, stream>>>(x, ln_w, ln_b, xn,
                                           Wa_w, WB_w, WC_w, Wab, WCb);
  gemm_bf16<false, 64, true><<<1024, 256, 0, stream>>>(xn, D_, Wab, D_, au, 512,
                                                       D_, 8, nullptr, nullptr, nullptr);
  fft_fwd<<<M_ / 8, 512, 0, stream>>>(au, Wa_b, WB_b, lg, ah, uh);
  scan_kernel<<<B_ * KB_, 512, 0, stream>>>(ah, uh);
  ifft_kernel<<<M_ / 8, 256, 0, stream>>>(uh, hb);
  gemm_bf16<true, 128, false><<<1024, 256, 0, stream>>>(hb, N_, WCb, N_, out, D_,
                                                        N_, 8, WC_b, D_skip, x);
}

// Round 7
// 108.106 us; speedup vs baseline: 1.4311x; 1.0479x over previous
//
#include <hip/hip_runtime.h>

// CirculantSSMLayer on MI355X.
// Pipeline: LN(+weight-prep) -> bf16 MFMA GEMM (Wa|WB fused) -> packed real FFT256
//           -> per-(b,k) block-scan over T -> packed inverse FFT -> bf16 MFMA GEMM + epilogue.
// R7: radix-4 FFT/IFFT (4 stages, half the LDS traffic) + removal of all per-stage
//     barriers (each wave owns its row; same-wave LDS ops are program-ordered).

typedef unsigned short ushort_t;
typedef short s16x8 __attribute__((ext_vector_type(8)));
typedef float f32x4 __attribute__((ext_vector_type(4)));
typedef _Float16 f16x8 __attribute__((ext_vector_type(8)));
typedef _Float16 f16x2 __attribute__((ext_vector_type(2)));

#define B_ 4
#define T_ 4096
#define D_ 1024
#define N_ 256
#define KB_ 129
#define M_ (B_*T_)

// LDS bank swizzle for float2 arrays: XOR bits 4-5 into bits 1-2 (involution).
#define SWZ(i) ((i) ^ (((i) >> 3) & 6))
// base-4 digit reversal of an 8-bit index (radix-4 FFT input scramble)
#define DR4(n) ((((n) & 3) << 6) | (((n) & 12) << 2) | (((n) & 48) >> 2) | (((n) >> 6) & 3))

__device__ __forceinline__ ushort_t f2bf(float f) {
  unsigned u = __float_as_uint(f);
  u = (u + 0x7FFFu + ((u >> 16) & 1u)) >> 16;
  return (ushort_t)u;
}
__device__ __forceinline__ float2 cmul(float2 a, float2 b) {
  return make_float2(a.x*b.x - a.y*b.y, a.x*b.y + a.y*b.x);
}
__device__ __forceinline__ float fast_tanh(float x) {
  return 1.f - 2.f / (__expf(2.f * x) + 1.f);
}

typedef const __attribute__((address_space(1))) unsigned glb_u32;
typedef __attribute__((address_space(3))) unsigned lds_u32;
__device__ __forceinline__ void gload16(const void* g, void* l) {
  __builtin_amdgcn_global_load_lds((glb_u32*)g, (lds_u32*)l, 16, 0, 0);
}

// ---------------- layernorm (blocks 0..4095) + weight f32->bf16 (blocks 4096..4863) ----
__global__ __launch_bounds__(256) void ln_prep_kernel(const float* __restrict__ x,
    const float* __restrict__ w, const float* __restrict__ bb,
    ushort_t* __restrict__ xn,
    const float* __restrict__ Wa, const float* __restrict__ WB,
    const float* __restrict__ WC, ushort_t* __restrict__ Wab,
    ushort_t* __restrict__ WCb) {
  int tid = threadIdx.x;
  if (blockIdx.x >= 4096) {
    int i4 = ((blockIdx.x - 4096) * 256 + tid) * 4;
    float4 v;
    ushort_t* dst;
    if (i4 < 262144)        { v = *(const float4*)(Wa + i4);          dst = Wab + i4; }
    else if (i4 < 524288)   { v = *(const float4*)(WB + i4 - 262144); dst = Wab + i4; }
    else                    { v = *(const float4*)(WC + i4 - 524288); dst = WCb + i4 - 524288; }
    ushort4 o;
    o.x = f2bf(v.x); o.y = f2bf(v.y); o.z = f2bf(v.z); o.w = f2bf(v.w);
    *(ushort4*)dst = o;
    return;
  }
  int lane = tid & 63, wv = tid >> 6;
  int row = blockIdx.x * 4 + wv;
  const float4* xr = (const float4*)(x + (size_t)row * D_);
  float4 v[4];
  float s = 0.f, sq = 0.f;
  #pragma unroll
  for (int j = 0; j < 4; ++j) {
    v[j] = xr[lane + 64 * j];
    s  += v[j].x + v[j].y + v[j].z + v[j].w;
    sq += v[j].x*v[j].x + v[j].y*v[j].y + v[j].z*v[j].z + v[j].w*v[j].w;
  }
  #pragma unroll
  for (int off = 32; off >= 1; off >>= 1) {
    s  += __shfl_xor(s, off);
    sq += __shfl_xor(sq, off);
  }
  float mu  = s * (1.0f / D_);
  float var = sq * (1.0f / D_) - mu * mu;
  float rs  = rsqrtf(var + 1e-5f);
  const float4* w4 = (const float4*)w;
  const float4* b4 = (const float4*)bb;
  ushort4* o4 = (ushort4*)(xn + (size_t)row * D_);
  #pragma unroll
  for (int j = 0; j < 4; ++j) {
    float4 wv_ = w4[lane + 64 * j];
    float4 bv_ = b4[lane + 64 * j];
    ushort4 o;
    o.x = f2bf((v[j].x - mu) * rs * wv_.x + bv_.x);
    o.y = f2bf((v[j].y - mu) * rs * wv_.y + bv_.y);
    o.z = f2bf((v[j].z - mu) * rs * wv_.z + bv_.z);
    o.w = f2bf((v[j].w - mu) * rs * wv_.w + bv_.w);
    o4[lane + 64 * j] = o;
  }
}

// ---------------- bf16 MFMA GEMM: C[m][n] = sum_k A[m][k]*B[n][k] ----------------
// BM=128 x BN tile, BK=64, 4 waves (2x2), 16x16x32 MFMA, global_load_lds width-16,
// 2 barriers per K-step. LDS rows = 64 shorts (128B): granule-XOR swizzle,
// slot = gk ^ (row&7); staged via pre-swizzled per-lane GLOBAL source.
template<bool EPI, int BN, bool HOUT>
__global__ __launch_bounds__(256) void gemm_bf16(
    const ushort_t* __restrict__ A, int lda,
    const ushort_t* __restrict__ B, int ldb,
    void* __restrict__ Cv, int ldc,
    int K, int ntiles,
    const float* __restrict__ bias,
    const float* __restrict__ dskip,
    const float* __restrict__ xres) {
  constexpr int NF = BN / 32;          // N fragments per wave
  __shared__ ushort_t Alds[128 * 64];
  __shared__ ushort_t Blds[BN * 64];
  int bid = blockIdx.x;
  int cpx = gridDim.x >> 3;
  bid = (bid & 7) * cpx + (bid >> 3);
  int mt = bid / ntiles, nt = bid % ntiles;
  int m0 = mt * 128, n0 = nt * BN;
  int tid = threadIdx.x;
  int lane = tid & 63, wid = tid >> 6;
  int wm = wid >> 1, wn = wid & 1;

  int lr8 = lane >> 3;                  // 0..7 (and row&7 for every staged row)
  int gd  = (lane & 7) ^ lr8;           // source data granule (pre-swizzled)
  const ushort_t* gA = A + (size_t)(m0 + wid * 32 + lr8) * lda + gd * 8;
  ushort_t* lA = &Alds[(wid * 32) * 64];
  constexpr int BROWS = BN / 4;         // B rows staged per wave (16 or 32)
  const ushort_t* gB = B + (size_t)(n0 + wid * BROWS + lr8) * ldb + gd * 8;
  ushort_t* lB = &Blds[(wid * BROWS) * 64];

  f32x4 acc[4][NF] = {};
  int rbase = lane & 15;
  int rb7 = lane & 7;
  int gk0 = lane >> 4;                  // k-granule 0..3 (+4 for kk=1)

  for (int k0 = 0; k0 < K; k0 += 64) {
    __syncthreads();
    #pragma unroll
    for (int c = 0; c < 4; ++c)
      gload16(gA + (size_t)(c * 8) * lda + k0, lA + c * 8 * 64);
    #pragma unroll
    for (int c = 0; c < BROWS / 8; ++c)
      gload16(gB + (size_t)(c * 8) * ldb + k0, lB + c * 8 * 64);
    __syncthreads();
    #pragma unroll
    for (int kk = 0; kk < 2; ++kk) {
      int sl = ((gk0 + kk * 4) ^ rb7) * 8;
      s16x8 af[4], bf[NF];
      #pragma unroll
      for (int i = 0; i < 4; ++i)
        af[i] = *reinterpret_cast<const s16x8*>(&Alds[(wm * 64 + i * 16 + rbase) * 64 + sl]);
      #pragma unroll
      for (int j = 0; j < NF; ++j)
        bf[j] = *reinterpret_cast<const s16x8*>(&Blds[(wn * (BN / 2) + j * 16 + rbase) * 64 + sl]);
      #pragma unroll
      for (int i = 0; i < 4; ++i)
        #pragma unroll
        for (int j = 0; j < NF; ++j)
          acc[i][j] = __builtin_amdgcn_mfma_f32_16x16x32_bf16(af[i], bf[j], acc[i][j], 0, 0, 0);
    }
  }

  int r0 = (lane >> 4) * 4, cc = lane & 15;
  #pragma unroll
  for (int i = 0; i < 4; ++i) {
    #pragma unroll
    for (int j = 0; j < NF; ++j) {
      int col = n0 + wn * (BN / 2) + j * 16 + cc;
      #pragma unroll
      for (int r = 0; r < 4; ++r) {
        int row = m0 + wm * 64 + i * 16 + r0 + r;
        float v = acc[i][j][r];
        if constexpr (EPI) v += bias[col] + dskip[col] * xres[(size_t)row * ldc + col];
        if constexpr (HOUT) ((_Float16*)Cv)[(size_t)row * ldc + col] = (_Float16)v;
        else                ((float*)Cv)[(size_t)row * ldc + col] = v;
      }
    }
  }
}

// ---------------- forward: bias+tanh+gate, packed radix-4 FFT256 ----------------
// Block: 512 threads = 8 rows (one wave each). z = a + i*u, one FFT serves both.
// Radix-4 DIT, dr4-scrambled input, natural-order output. Each wave owns its row:
// no per-stage barriers (same-wave LDS ops are program-ordered).
__global__ __launch_bounds__(512) void fft_fwd(const _Float16* __restrict__ au,
    const float* __restrict__ ba, const float* __restrict__ bu,
    const float* __restrict__ lg, _Float16* __restrict__ ah, _Float16* __restrict__ uh) {
  __shared__ float2 Z[8][256];
  __shared__ float2 Tw[256];
  int tid = threadIdx.x;
  int m0 = blockIdx.x * 8;
  int tg = tid >> 6, lane = tid & 63;
  if (tid < 256) {
    float sn, cs;
    __sincosf(-6.2831853071795864f / 256.f * (float)tid, &sn, &cs);
    Tw[tid] = make_float2(cs, sn);
  }
  float gamma = 1.f / (1.f + __expf(-lg[0]));
  const _Float16* row = au + (size_t)(m0 + tg) * (2 * N_);
  #pragma unroll
  for (int j = 0; j < 4; ++j) {
    int n = lane + 64 * j;
    float a = gamma * fast_tanh((float)row[n] + ba[n]);
    float u = (float)row[N_ + n] + bu[n];
    Z[tg][SWZ(DR4(n))] = make_float2(a, u);
  }
  __syncthreads();   // covers Tw init (cross-wave) + own-row input writes
  #pragma unroll
  for (int ls = 0; ls < 4; ++ls) {     // L = 4,16,64,256
    const int Q = 1 << (2 * ls);
    const int step = 64 >> (2 * ls);   // 256/L
    int j = lane & (Q - 1);
    int g = lane >> (2 * ls);
    int base = g * (4 * Q) + j;
    float2 a0 = Z[tg][SWZ(base)];
    float2 a1 = Z[tg][SWZ(base + Q)];
    float2 a2 = Z[tg][SWZ(base + 2 * Q)];
    float2 a3 = Z[tg][SWZ(base + 3 * Q)];
    if (ls > 0) {
      int e = j * step;
      a1 = cmul(a1, Tw[e]);
      a2 = cmul(a2, Tw[2 * e]);
      a3 = cmul(a3, Tw[3 * e]);
    }
    float2 t0 = make_float2(a0.x + a2.x, a0.y + a2.y);
    float2 t1 = make_float2(a0.x - a2.x, a0.y - a2.y);
    float2 t2 = make_float2(a1.x + a3.x, a1.y + a3.y);
    float2 d  = make_float2(a1.x - a3.x, a1.y - a3.y);
    float2 t3 = make_float2(d.y, -d.x);          // -i*(a1-a3): forward
    Z[tg][SWZ(base)]         = make_float2(t0.x + t2.x, t0.y + t2.y);
    Z[tg][SWZ(base + Q)]     = make_float2(t1.x + t3.x, t1.y + t3.y);
    Z[tg][SWZ(base + 2 * Q)] = make_float2(t0.x - t2.x, t0.y - t2.y);
    Z[tg][SWZ(base + 3 * Q)] = make_float2(t1.x - t3.x, t1.y - t3.y);
  }
  __syncthreads();   // extract reads other waves' rows
  int b = m0 >> 12, tb = m0 & (T_ - 1);
  #pragma unroll
  for (int p = 0; p < 3; ++p) {
    int k = (tid >> 3) + p * 64;
    int tl = tid & 7;
    if (k <= 128) {
      float2 zk = Z[tl][SWZ(k)];
      float2 zn = Z[tl][SWZ((256 - k) & 255)];
      float2 Af = make_float2(0.5f * (zk.x + zn.x), 0.5f * (zk.y - zn.y));
      float2 Uf = make_float2(0.5f * (zk.y + zn.y), -0.5f * (zk.x - zn.x));
      float mag = fmaxf(sqrtf(Af.x * Af.x + Af.y * Af.y), 1e-8f);
      float scl = 1.f / (1.f + __expf(-2.f * (1.f - mag)));
      Af.x *= scl; Af.y *= scl;
      size_t off2 = (((size_t)(b * KB_ + k)) * T_ + tb + tl) * 2;
      f16x2 av; av[0] = (_Float16)Af.x; av[1] = (_Float16)Af.y;
      f16x2 uv; uv[0] = (_Float16)Uf.x; uv[1] = (_Float16)Uf.y;
      *(f16x2*)(ah + off2) = av;
      *(f16x2*)(uh + off2) = uv;
    }
  }
}

// ---------------- time scan: h_t = a_t*h_{t-1} + u_t per (b,k) chain ----------------
// fp16 at-rest, f32 compute. 512 threads x 8 complex each; shuffle-scan + 1 barrier.
__global__ __launch_bounds__(512) void scan_kernel(const _Float16* __restrict__ ah,
                                                   _Float16* __restrict__ uh) {
  __shared__ float4 wagg[8];
  int tid = threadIdx.x;
  int lane = tid & 63, wv = tid >> 6;
  size_t base = (size_t)blockIdx.x * T_ * 2;
  const f16x8* a8 = (const f16x8*)(ah + base);
  f16x8* u8 = (f16x8*)(uh + base);
  f16x8 Av[2], Uv[2];
  #pragma unroll
  for (int q = 0; q < 2; ++q) { Av[q] = a8[tid * 2 + q]; Uv[q] = u8[tid * 2 + q]; }
  float2 La[8], Lb[8];
  float2 ra = make_float2(1.f, 0.f), rb = make_float2(0.f, 0.f);
  #pragma unroll
  for (int e = 0; e < 8; ++e) {
    const int q = e >> 2, i = (e & 3) * 2;
    float2 a = make_float2((float)Av[q][i], (float)Av[q][i + 1]);
    float2 u = make_float2((float)Uv[q][i], (float)Uv[q][i + 1]);
    float2 t = cmul(a, rb);
    rb = make_float2(t.x + u.x, t.y + u.y);
    ra = cmul(ra, a);
    La[e] = ra; Lb[e] = rb;
  }
  #pragma unroll
  for (int off = 1; off < 64; off <<= 1) {
    float ax = __shfl_up(ra.x, off, 64), ay = __shfl_up(ra.y, off, 64);
    float bx = __shfl_up(rb.x, off, 64), by = __shfl_up(rb.y, off, 64);
    if (lane >= off) {
      float2 Ap = make_float2(ax, ay), Bp = make_float2(bx, by);
      float2 nB = cmul(ra, Bp);
      nB.x += rb.x; nB.y += rb.y;
      ra = cmul(Ap, ra);
      rb = nB;
    }
  }
  if (lane == 63) wagg[wv] = make_float4(ra.x, ra.y, rb.x, rb.y);
  __syncthreads();
  float2 Bw = make_float2(0.f, 0.f);
  for (int w0 = 0; w0 < wv; ++w0) {
    float4 g = wagg[w0];
    float2 gA = make_float2(g.x, g.y), gB = make_float2(g.z, g.w);
    Bw = cmul(gA, Bw);
    Bw.x += gB.x; Bw.y += gB.y;
  }
  float ax = __shfl_up(ra.x, 1, 64), ay = __shfl_up(ra.y, 1, 64);
  float bx = __shfl_up(rb.x, 1, 64), by = __shfl_up(rb.y, 1, 64);
  float2 Ae, Be;
  if (lane == 0) { Ae = make_float2(1.f, 0.f); Be = make_float2(0.f, 0.f); }
  else           { Ae = make_float2(ax, ay);   Be = make_float2(bx, by);   }
  float2 Pb = cmul(Ae, Bw);
  Pb.x += Be.x; Pb.y += Be.y;
  #pragma unroll
  for (int q = 0; q < 2; ++q) {
    f16x8 o;
    #pragma unroll
    for (int e2 = 0; e2 < 4; ++e2) {
      const int e = q * 4 + e2;
      float2 h = cmul(La[e], Pb);
      h.x += Lb[e].x; h.y += Lb[e].y;
      o[e2 * 2]     = (_Float16)h.x;
      o[e2 * 2 + 1] = (_Float16)h.y;
    }
    u8[tid * 2 + q] = o;
  }
}

// ---------------- inverse radix-4 FFT: 2 real rows per complex transform -> h bf16 ----
// Block: 256 threads = 8 rows = 4 transforms (one wave each). No per-stage barriers.
__global__ __launch_bounds__(256) void ifft_kernel(const _Float16* __restrict__ hh,
                                                   ushort_t* __restrict__ hb) {
  __shared__ float2 Hraw[8][132];
  __shared__ float2 Wz[4][256];
  __shared__ float2 Tw[256];
  int tid = threadIdx.x;
  int m0 = blockIdx.x * 8;
  int b = m0 >> 12, tb = m0 & (T_ - 1);
  {
    float sn, cs;
    __sincosf(6.2831853071795864f / 256.f * (float)tid, &sn, &cs);
    Tw[tid] = make_float2(cs, sn);
  }
  #pragma unroll
  for (int p = 0; p < 5; ++p) {
    int k = p * 32 + (tid >> 3), tl = tid & 7;
    if (k <= 128) {
      f16x2 hv = *(const f16x2*)(hh + (((size_t)(b * KB_ + k)) * T_ + tb + tl) * 2);
      Hraw[tl][k] = make_float2((float)hv[0], (float)hv[1]);
    }
  }
  __syncthreads();
  #pragma unroll
  for (int p = 0; p < 3; ++p) {
    int idx = p * 256 + tid;
    if (idx < 516) {
      int k = idx >> 2, pr = idx & 3;
      float2 h1 = Hraw[2 * pr][k], h2 = Hraw[2 * pr + 1][k];
      Wz[pr][SWZ(DR4(k))] = make_float2(h1.x - h2.y, h1.y + h2.x);
      if (k >= 1 && k <= 127)
        Wz[pr][SWZ(DR4(256 - k))] = make_float2(h1.x + h2.y, h2.x - h1.y);
    }
  }
  __syncthreads();   // construction is cross-wave; transform below is own-row
  int pr = tid >> 6, lane = tid & 63;
  #pragma unroll
  for (int ls = 0; ls < 4; ++ls) {     // L = 4,16,64,256
    const int Q = 1 << (2 * ls);
    const int step = 64 >> (2 * ls);
    int j = lane & (Q - 1);
    int g = lane >> (2 * ls);
    int base = g * (4 * Q) + j;
    float2 a0 = Wz[pr][SWZ(base)];
    float2 a1 = Wz[pr][SWZ(base + Q)];
    float2 a2 = Wz[pr][SWZ(base + 2 * Q)];
    float2 a3 = Wz[pr][SWZ(base + 3 * Q)];
    if (ls > 0) {
      int e = j * step;
      a1 = cmul(a1, Tw[e]);
      a2 = cmul(a2, Tw[2 * e]);
      a3 = cmul(a3, Tw[3 * e]);
    }
    float2 t0 = make_float2(a0.x + a2.x, a0.y + a2.y);
    float2 t1 = make_float2(a0.x - a2.x, a0.y - a2.y);
    float2 t2 = make_float2(a1.x + a3.x, a1.y + a3.y);
    float2 d  = make_float2(a1.x - a3.x, a1.y - a3.y);
    float2 t3 = make_float2(-d.y, d.x);          // +i*(a1-a3): inverse
    Wz[pr][SWZ(base)]         = make_float2(t0.x + t2.x, t0.y + t2.y);
    Wz[pr][SWZ(base + Q)]     = make_float2(t1.x + t3.x, t1.y + t3.y);
    Wz[pr][SWZ(base + 2 * Q)] = make_float2(t0.x - t2.x, t0.y - t2.y);
    Wz[pr][SWZ(base + 3 * Q)] = make_float2(t1.x - t3.x, t1.y - t3.y);
  }
  const float inv = 1.f / 256.f;
  #pragma unroll
  for (int j = 0; j < 4; ++j) {
    int n = lane + 64 * j;
    float2 wv = Wz[pr][SWZ(n)];
    hb[(size_t)(m0 + 2 * pr) * N_ + n]     = f2bf(wv.x * inv);
    hb[(size_t)(m0 + 2 * pr + 1) * N_ + n] = f2bf(wv.y * inv);
  }
}

// ---------------- launch ----------------
extern "C" void kernel_launch(void* const* d_in, const int* in_sizes, int n_in,
                              void* d_out, int out_size, void* d_ws, size_t ws_size,
                              hipStream_t stream) {
  const float* x      = (const float*)d_in[0];
  const float* Wa_w   = (const float*)d_in[1];
  const float* Wa_b   = (const float*)d_in[2];
  const float* lg     = (const float*)d_in[3];
  const float* WB_w   = (const float*)d_in[4];
  const float* WB_b   = (const float*)d_in[5];
  const float* WC_w   = (const float*)d_in[6];
  const float* WC_b   = (const float*)d_in[7];
  const float* D_skip = (const float*)d_in[8];
  const float* ln_w   = (const float*)d_in[9];
  const float* ln_b   = (const float*)d_in[10];
  float* out = (float*)d_out;
  char* ws = (char*)d_ws;

  // Workspace (lifetime-overlapped):
  //   [0, 33.55MB): xn bf16 (early) | ah fp16 spectra 8.45MB + uh fp16 at 16.9MB (late)
  //   [33.55MB, 34.60MB): Wab bf16 (dead after gemm1)
  //   [34.60MB, 35.13MB): WCb bf16 (whole run)
  //   [35.13MB, +16.8MB): au fp16 (dead after fft) | hb bf16 8.4MB (late)
  ushort_t*  xn  = (ushort_t*)(ws + 0);
  ushort_t*  Wab = (ushort_t*)(ws + 33554432);
  ushort_t*  WCb = (ushort_t*)(ws + 34603008);
  _Float16*  au  = (_Float16*)(ws + 35127296);
  ushort_t*  hb  = (ushort_t*)(ws + 35127296);   // aliases au (dead by then)
  _Float16*  ah  = (_Float16*)(ws + 0);          // aliases xn (dead by then)
  _Float16*  uh  = (_Float16*)(ws + 16908288);   // h_hat written in place

  ln_prep_kernel<<<4864, 256, 0, stream>>>(x, ln_w, ln_b, xn,
                                           Wa_w, WB_w, WC_w, Wab, WCb);
  gemm_bf16<false, 64, true><<<1024, 256, 0, stream>>>(xn, D_, Wab, D_, au, 512,
                                                       D_, 8, nullptr, nullptr, nullptr);
  fft_fwd<<<M_ / 8, 512, 0, stream>>>(au, Wa_b, WB_b, lg, ah, uh);
  scan_kernel<<<B_ * KB_, 512, 0, stream>>>(ah, uh);
  ifft_kernel<<<M_ / 8, 256, 0, stream>>>(uh, hb);
  gemm_bf16<true, 128, false><<<1024, 256, 0, stream>>>(hb, N_, WCb, N_, out, D_,
                                                        N_, 8, WC_b, D_skip, x);
}